// Round 1
// 380.389 us; speedup vs baseline: 1.0795x; 1.0795x over previous
//
#include <hip/hip_runtime.h>
#include <hip/hip_bf16.h>
#include <cstdint>
#include <cstddef>

typedef short short8 __attribute__((ext_vector_type(8)));
typedef short short4v __attribute__((ext_vector_type(4)));
typedef float floatx4 __attribute__((ext_vector_type(4)));

constexpr int Bz = 4;
constexpr int Lz = 4096;
constexpr int Dm = 1024;       // d_model
constexpr int Di = 1024;       // d_inner
constexpr int Mrows = Bz * Lz; // 16384
constexpr int CH  = 128;       // scan chunk length
constexpr int NCH = Lz / CH;   // 32
constexpr int XPJ_KS = 4;      // x_proj split-K factor

__device__ __forceinline__ void load16(const void* g, void* l) {
  __builtin_amdgcn_global_load_lds((__attribute__((address_space(1))) void*)g,
                                   (__attribute__((address_space(3))) void*)l,
                                   16, 0, 0);
}

__device__ __forceinline__ float bf2f(const __hip_bfloat16 v) { return __bfloat162float(v); }
__device__ __forceinline__ short f2bfs(float v) {
  __hip_bfloat16 h = __float2bfloat16(v);
  return *(short*)&h;
}

// ---------------------------------------------------------------------------
// f32 -> bf16 conversion, 4 elements/thread.
// ---------------------------------------------------------------------------
__global__ __launch_bounds__(256) void cvt_bf16(const float* __restrict__ in,
                                                __hip_bfloat16* __restrict__ out, int n4)
{
  const int i = blockIdx.x * 256 + threadIdx.x;
  if (i >= n4) return;
  const float4 v = ((const float4*)in)[i];
  short4v s;
  s[0] = f2bfs(v.x); s[1] = f2bfs(v.y); s[2] = f2bfs(v.z); s[3] = f2bfs(v.w);
  ((short4v*)out)[i] = s;
}

// All 4 weight matrices in one launch. Ranges in units of 4 floats.
__global__ __launch_bounds__(256) void cvt_weights(
    const float* __restrict__ w_in, const float* __restrict__ w_out,
    const float* __restrict__ xpw, const float* __restrict__ dtw,
    __hip_bfloat16* __restrict__ w_in_bf, __hip_bfloat16* __restrict__ w_out_bf,
    __hip_bfloat16* __restrict__ xpw_bf, __hip_bfloat16* __restrict__ dtw_bf)
{
  const int i = blockIdx.x * 256 + threadIdx.x;
  const float* src; __hip_bfloat16* dst; int j;
  if (i < 524288)      { src = w_in;  dst = w_in_bf;  j = i; }
  else if (i < 786432) { src = w_out; dst = w_out_bf; j = i - 524288; }
  else if (i < 803328) { src = xpw;   dst = xpw_bf;   j = i - 786432; }
  else if (i < 819712) { src = dtw;   dst = dtw_bf;   j = i - 803328; }
  else return;
  const float4 v = ((const float4*)src)[j];
  short4v s;
  s[0] = f2bfs(v.x); s[1] = f2bfs(v.y); s[2] = f2bfs(v.z); s[3] = f2bfs(v.w);
  ((short4v*)dst)[j] = s;
}

// ---------------------------------------------------------------------------
// 128x128 MFMA GEMM (m97-class structure). Retained ONLY for the K=64
// delta GEMM (EPI 1), which is memory-bound.
// ---------------------------------------------------------------------------
template <int EPI>
__global__ __launch_bounds__(256) void gemm128(
    const __hip_bfloat16* __restrict__ A,
    const __hip_bfloat16* __restrict__ W,
    int K, int N,
    __hip_bfloat16* __restrict__ outb0,
    __hip_bfloat16* __restrict__ outb1,
    float* __restrict__ outf,
    const float* __restrict__ biasf)
{
  constexpr int BK = 32;
  constexpr int GY = 16;
  __shared__ short sA[128 * BK];
  __shared__ short sB[128 * BK];
  const int tid  = threadIdx.x;
  const int wid  = tid >> 6;
  const int lane = tid & 63;

  const int gx  = gridDim.x;
  const int id  = blockIdx.y * gx + blockIdx.x;
  const int seg = gx * GY;
  const int bx  = (id % seg) / GY;
  const int by  = (id / seg) * GY + (id % GY);

  const int m0 = by * 128;
  const int n0 = bx * 128;
  const int wm = (wid & 1) * 64;
  const int wn = (wid >> 1) * 64;

  floatx4 acc[4][4];
#pragma unroll
  for (int i = 0; i < 4; i++)
#pragma unroll
    for (int j = 0; j < 4; j++) acc[i][j] = (floatx4){0.f, 0.f, 0.f, 0.f};

  const short* Ag = (const short*)A + (size_t)(m0 + (tid >> 2)) * K + (tid & 3) * 8;
  const short* Bg = (const short*)W + (size_t)(n0 + (tid >> 2)) * K + (tid & 3) * 8;
  short* sAd = &sA[tid * 8];
  short* sBd = &sB[tid * 8];
  const size_t rstep = (size_t)64 * K;
  const int fr = lane & 15, fq = lane >> 4;

  for (int kb = 0; kb < K; kb += BK) {
    load16(Ag, sAd);
    load16(Ag + rstep, sAd + 2048);
    load16(Bg, sBd);
    load16(Bg + rstep, sBd + 2048);
    Ag += BK; Bg += BK;
    __syncthreads();

    short8 av[4], bv[4];
#pragma unroll
    for (int mt = 0; mt < 4; mt++) av[mt] = *(const short8*)&sA[(wm + mt * 16 + fr) * BK + fq * 8];
#pragma unroll
    for (int nt = 0; nt < 4; nt++) bv[nt] = *(const short8*)&sB[(wn + nt * 16 + fr) * BK + fq * 8];
#pragma unroll
    for (int mt = 0; mt < 4; mt++)
#pragma unroll
      for (int nt = 0; nt < 4; nt++)
        acc[mt][nt] = __builtin_amdgcn_mfma_f32_16x16x32_bf16(av[mt], bv[nt], acc[mt][nt], 0, 0, 0);
    __syncthreads();
  }

#pragma unroll
  for (int mt = 0; mt < 4; mt++) {
#pragma unroll
    for (int nt = 0; nt < 4; nt++) {
#pragma unroll
      for (int r = 0; r < 4; r++) {
        const int gm = m0 + wm + mt * 16 + fq * 4 + r;
        const int gn = n0 + wn + nt * 16 + fr;
        float v = acc[mt][nt][r];
        if constexpr (EPI == 0) {
          if (gn < 1024) outb0[(size_t)gm * 1024 + gn] = __float2bfloat16(v);
          else           outb1[(size_t)gm * 1024 + (gn - 1024)] = __float2bfloat16(v);
        } else if constexpr (EPI == 1) {
          v += biasf[gn];
          v = (v > 15.f) ? v : __logf(1.f + __expf(v));
          outb0[(size_t)gm * N + gn] = __float2bfloat16(v);
        } else {
          outf[(size_t)gm * N + gn] = v;
        }
      }
    }
  }
}

// ---------------------------------------------------------------------------
// 256x256 8-phase MFMA GEMM (T2 st_16x32 swizzle + T3/T4 counted vmcnt + T5
// setprio). C[M,N] = A[M,K] (bf16 rm) * W[N,K]^T (bf16 rm).
// 512 threads = 8 waves (2M x 4N), per-wave 128x64 output. BK=64.
// LDS 128 KiB: A[2buf][2half][16 subtiles(16x32)x1024B], B same at +64KB.
// Swizzle: within 1024B subtile, byte ^= ((row&8)?32:0). global_load_lds
// writes LINEAR LDS; the global SOURCE address is inverse-swizzled (rule #21).
//
// Stage-slot schedule (steady state, iteration t reads K-tile t from buf cur):
//   ph1: reads bv[0..3][0..1] + av[0,1][*] (12); stage A1(t+1) -> buf nxt
//   ph2: reads av[2,3][*] (4);               stage B0(t+2) -> buf cur
//   ph3: reads av[4..7][*] (8);              stage B1(t+2) -> buf cur
//   ph4: no reads;                           stage A0(t+2) -> buf cur
// Every overwrite of buf cur is fenced by the previous phase's per-wave
// lgkmcnt(0) + barrier (B reads end at ph1; A reads end at ph3).
// Landing: vmcnt(6)+barrier at ph4 leaves exactly this iter's ph2/3/4 stages
// (3 half-tiles = 6 loads) in flight => K-tile t+1 fully resident.
// EPI 0: n<1024 -> outb0 (bf16), else outb1 (bf16).  EPI 1: f32 out.
// ---------------------------------------------------------------------------
template <int EPI>
__device__ __forceinline__ void cluster_mfma(int MQ, floatx4 (&acc)[8][4],
                                             const short8 (&av)[8][2],
                                             const short8 (&bv)[4][2])
{
  __builtin_amdgcn_s_setprio(1);
#pragma unroll
  for (int j = 0; j < 2; j++)
#pragma unroll
    for (int nf = 0; nf < 4; nf++)
#pragma unroll
      for (int ks = 0; ks < 2; ks++)
        acc[2 * MQ + j][nf] = __builtin_amdgcn_mfma_f32_16x16x32_bf16(
            av[2 * MQ + j][ks], bv[nf][ks], acc[2 * MQ + j][nf], 0, 0, 0);
  __builtin_amdgcn_s_setprio(0);
}

template <int EPI>
__global__ __launch_bounds__(512, 2) void gemm256(
    const __hip_bfloat16* __restrict__ A,
    const __hip_bfloat16* __restrict__ W,
    int K, int N,
    __hip_bfloat16* __restrict__ outb0,
    __hip_bfloat16* __restrict__ outb1,
    float* __restrict__ outf)
{
  __shared__ alignas(16) char lds[131072];
  const int tid  = threadIdx.x;
  const int wid  = tid >> 6;
  const int lane = tid & 63;
  const int wm = wid >> 2;      // 0..1
  const int wn = wid & 3;       // 0..3
  const int fr = lane & 15, fq = lane >> 4;
  const int m0 = blockIdx.y * 256;
  const int n0 = blockIdx.x * 256;
  const size_t K2 = (size_t)K * 2;   // row bytes

  // Staging: thread chunk i covers LDS bytes p=(i*512+tid)*16 of a 16KB half.
  // Inverse-swizzle to find which global element belongs at linear byte p.
  int rowo[2], colo[2];
#pragma unroll
  for (int i = 0; i < 2; i++) {
    const int p = i * 8192 + tid * 16;
    const int s = p >> 10;           // subtile 0..15 (rb*2+cb)
    const int r = (p >> 6) & 15;     // row within subtile
    rowo[i] = (s >> 1) * 16 + r;                                  // 0..127
    colo[i] = (s & 1) * 64 + ((p & 63) ^ (((r >> 3) & 1) << 5));  // byte 0..127
  }
  const char* Ab = (const char*)A + (size_t)m0 * K2;
  const char* Bb = (const char*)W + (size_t)n0 * K2;
  char* lbase = (char*)lds;

#define STAGE_A(c, h, kt) do {                                                          \
    load16(Ab + (size_t)((h) * 128 + rowo[0]) * K2 + (size_t)(kt) * 128 + colo[0],      \
           lbase + (c) * 32768 + (h) * 16384 + tid * 16);                               \
    load16(Ab + (size_t)((h) * 128 + rowo[1]) * K2 + (size_t)(kt) * 128 + colo[1],      \
           lbase + (c) * 32768 + (h) * 16384 + 8192 + tid * 16);                        \
  } while (0)
#define STAGE_B(c, h, kt) do {                                                          \
    load16(Bb + (size_t)((h) * 128 + rowo[0]) * K2 + (size_t)(kt) * 128 + colo[0],      \
           lbase + 65536 + (c) * 32768 + (h) * 16384 + tid * 16);                       \
    load16(Bb + (size_t)((h) * 128 + rowo[1]) * K2 + (size_t)(kt) * 128 + colo[1],      \
           lbase + 65536 + (c) * 32768 + (h) * 16384 + 8192 + tid * 16);                \
  } while (0)

  // Fragment read offset within its 1024B subtile (swizzled, 16B aligned).
  const int foff = (fr * 64 + fq * 16) ^ (((fr >> 3) & 1) << 5);

  floatx4 acc[8][4];
#pragma unroll
  for (int i = 0; i < 8; i++)
#pragma unroll
    for (int j = 0; j < 4; j++) acc[i][j] = (floatx4){0.f, 0.f, 0.f, 0.f};

  // Prologue: K0 all 4 halves, then K1 {B0,B1,A0}. vmcnt(6) => K0 landed.
  STAGE_A(0, 0, 0); STAGE_A(0, 1, 0); STAGE_B(0, 0, 0); STAGE_B(0, 1, 0);
  STAGE_B(1, 0, 1); STAGE_B(1, 1, 1); STAGE_A(1, 0, 1);
  asm volatile("s_waitcnt vmcnt(6)\n\ts_barrier" ::: "memory");

  const int NT = K >> 6;
  short8 av[8][2], bv[4][2];
#pragma unroll 2
  for (int t = 0; t < NT; ++t) {
    const int cur = t & 1, nxt = cur ^ 1;
    const char* la = lbase + cur * 32768 + wm * 16384 + foff;
    const char* lb = lbase + 65536 + cur * 32768 + (wn >> 1) * 16384 + (wn & 1) * 8192 + foff;

    // ---------------- phase 1: all B frags + av[0,1]; stage A1(t+1)->nxt
#pragma unroll
    for (int nf = 0; nf < 4; nf++)
#pragma unroll
      for (int ks = 0; ks < 2; ks++)
        bv[nf][ks] = *(const short8*)(lb + (nf * 2 + ks) * 1024);
#pragma unroll
    for (int mf = 0; mf < 2; mf++)
#pragma unroll
      for (int ks = 0; ks < 2; ks++)
        av[mf][ks] = *(const short8*)(la + (mf * 2 + ks) * 1024);
    if (t + 1 < NT) STAGE_A(nxt, 1, t + 1);
    asm volatile("s_barrier" ::: "memory");
    asm volatile("s_waitcnt lgkmcnt(0)" ::: "memory");
    cluster_mfma<EPI>(0, acc, av, bv);
    asm volatile("s_barrier" ::: "memory");

    // ---------------- phase 2: av[2,3]; stage B0(t+2)->cur (B reads done ph1)
#pragma unroll
    for (int mf = 2; mf < 4; mf++)
#pragma unroll
      for (int ks = 0; ks < 2; ks++)
        av[mf][ks] = *(const short8*)(la + (mf * 2 + ks) * 1024);
    if (t + 2 < NT) STAGE_B(cur, 0, t + 2);
    asm volatile("s_barrier" ::: "memory");
    asm volatile("s_waitcnt lgkmcnt(0)" ::: "memory");
    cluster_mfma<EPI>(1, acc, av, bv);
    asm volatile("s_barrier" ::: "memory");

    // ---------------- phase 3: av[4..7]; stage B1(t+2)->cur
#pragma unroll
    for (int mf = 4; mf < 8; mf++)
#pragma unroll
      for (int ks = 0; ks < 2; ks++)
        av[mf][ks] = *(const short8*)(la + (mf * 2 + ks) * 1024);
    if (t + 2 < NT) STAGE_B(cur, 1, t + 2);
    asm volatile("s_barrier" ::: "memory");
    asm volatile("s_waitcnt lgkmcnt(0)" ::: "memory");
    cluster_mfma<EPI>(2, acc, av, bv);
    asm volatile("s_barrier" ::: "memory");

    // ---------------- phase 4: no reads; stage A0(t+2)->cur (A reads done ph3)
    if (t + 2 < NT) STAGE_A(cur, 0, t + 2);
    asm volatile("s_barrier" ::: "memory");
    cluster_mfma<EPI>(3, acc, av, bv);
    // counted vmcnt once per K-tile: 3 newest half-tiles (6 loads) in flight.
    if (t < NT - 2) {
      asm volatile("s_waitcnt vmcnt(6)\n\ts_barrier" ::: "memory");
    } else if (t == NT - 2) {
      asm volatile("s_waitcnt vmcnt(0)\n\ts_barrier" ::: "memory");
    } // t == NT-1: fall through to epilogue
  }
#undef STAGE_A
#undef STAGE_B

#pragma unroll
  for (int mf = 0; mf < 8; mf++) {
#pragma unroll
    for (int nf = 0; nf < 4; nf++) {
#pragma unroll
      for (int r = 0; r < 4; r++) {
        const int gm = m0 + wm * 128 + mf * 16 + fq * 4 + r;
        const int gn = n0 + wn * 64 + nf * 16 + fr;
        const float v = acc[mf][nf][r];
        if constexpr (EPI == 0) {
          if (gn < 1024) outb0[(size_t)gm * 1024 + gn] = __float2bfloat16(v);
          else           outb1[(size_t)gm * 1024 + (gn - 1024)] = __float2bfloat16(v);
        } else {
          outf[(size_t)gm * N + gn] = v;
        }
      }
    }
  }
}

// ---------------------------------------------------------------------------
// x_proj GEMM, split-K x4: partial[kc][M,66] = u[M, kc-chunk] * xpw[66, kc-chunk]^T
// ---------------------------------------------------------------------------
__global__ __launch_bounds__(256) void gemm_xproj(
    const __hip_bfloat16* __restrict__ A,
    const __hip_bfloat16* __restrict__ W,
    float* __restrict__ part)
{
  constexpr int K = 1024, BK = 32, KC = K / XPJ_KS; // 256
  __shared__ short sA[128 * BK];
  __shared__ short sB[80 * BK];
  const int tid = threadIdx.x;
  const int wid = tid >> 6, lane = tid & 63;
  const int kc = blockIdx.x;
  const int m0 = blockIdx.y * 128;

  floatx4 acc[2][5];
#pragma unroll
  for (int i = 0; i < 2; i++)
#pragma unroll
    for (int j = 0; j < 5; j++) acc[i][j] = (floatx4){0.f, 0.f, 0.f, 0.f};

  const short* Ag = (const short*)A + (size_t)(m0 + (tid >> 2)) * K + kc * KC + (tid & 3) * 8;
  const int brow2 = 64 + (tid >> 2);
  const int brow2c = brow2 > 65 ? 65 : brow2;
  const short* Bg  = (const short*)W + (size_t)(tid >> 2) * K + kc * KC + (tid & 3) * 8;
  const short* Bg2 = (const short*)W + (size_t)brow2c * K + kc * KC + (tid & 3) * 8;
  const size_t rstep = (size_t)64 * K;
  const int fr = lane & 15, fq = lane >> 4;

  for (int kb = 0; kb < KC; kb += BK) {
    load16(Ag, &sA[tid * 8]);
    load16(Ag + rstep, &sA[2048 + tid * 8]);
    load16(Bg, &sB[tid * 8]);
    if (tid < 64) load16(Bg2, &sB[2048 + tid * 8]);
    Ag += BK; Bg += BK; Bg2 += BK;
    __syncthreads();

    short8 av[2], bv[5];
#pragma unroll
    for (int mt = 0; mt < 2; mt++) av[mt] = *(const short8*)&sA[(wid * 32 + mt * 16 + fr) * BK + fq * 8];
#pragma unroll
    for (int nt = 0; nt < 5; nt++) bv[nt] = *(const short8*)&sB[(nt * 16 + fr) * BK + fq * 8];
#pragma unroll
    for (int mt = 0; mt < 2; mt++)
#pragma unroll
      for (int nt = 0; nt < 5; nt++)
        acc[mt][nt] = __builtin_amdgcn_mfma_f32_16x16x32_bf16(av[mt], bv[nt], acc[mt][nt], 0, 0, 0);
    __syncthreads();
  }

  float* pp = part + (size_t)kc * Mrows * 66;
#pragma unroll
  for (int mt = 0; mt < 2; mt++) {
#pragma unroll
    for (int nt = 0; nt < 5; nt++) {
#pragma unroll
      for (int r = 0; r < 4; r++) {
        const int gm = m0 + wid * 32 + mt * 16 + fq * 4 + r;
        const int gn = nt * 16 + fr;
        if (gn < 66) pp[(size_t)gm * 66 + gn] = acc[mt][nt][r];
      }
    }
  }
}

__global__ __launch_bounds__(256) void xproj_reduce(
    const float* __restrict__ part,
    __hip_bfloat16* __restrict__ dts,
    float* __restrict__ Bs, float* __restrict__ Cs)
{
  const int i = blockIdx.x * 256 + threadIdx.x;
  if (i >= Mrows * 66) return;
  const int gm = i / 66, gn = i - gm * 66;
  float s = part[i] + part[i + (size_t)Mrows * 66]
          + part[i + (size_t)2 * Mrows * 66] + part[i + (size_t)3 * Mrows * 66];
  if (gn < 64)       dts[(size_t)gm * 64 + gn] = __float2bfloat16(s);
  else if (gn == 64) Bs[gm] = s;
  else               Cs[gm] = s;
}

// ---------------------------------------------------------------------------
// Causal depthwise conv (k=2) + bias + SiLU.  bf16 data, f32 params.
// ---------------------------------------------------------------------------
__global__ __launch_bounds__(256) void conv_silu(
    const __hip_bfloat16* __restrict__ xc, const float* __restrict__ cw,
    const float* __restrict__ cb, __hip_bfloat16* __restrict__ u)
{
  const size_t idx = (size_t)blockIdx.x * 256 + threadIdx.x;
  const int d = (int)(idx & (Di - 1));
  const int l = (int)((idx >> 10) & (Lz - 1));
  const float w0 = cw[2 * d], w1 = cw[2 * d + 1];
  const float prev = (l > 0) ? bf2f(xc[idx - Di]) : 0.f;
  const float v = prev * w0 + bf2f(xc[idx]) * w1 + cb[d];
  const float s = v / (1.f + __expf(-v));
  u[idx] = __float2bfloat16(s);
}

// ---------------------------------------------------------------------------
// Chunked scan, D_STATE=1:  h[l] = exp(delta*A)*h[l-1] + delta*Bs*u
// ---------------------------------------------------------------------------
__global__ __launch_bounds__(256) void scan_p1(
    const __hip_bfloat16* __restrict__ delta, const __hip_bfloat16* __restrict__ u,
    const float* __restrict__ Bsv, const float* __restrict__ A_logs,
    float* __restrict__ carryP, float* __restrict__ carryS)
{
  const int d = blockIdx.x * 256 + threadIdx.x;
  const int c = blockIdx.y, b = blockIdx.z;
  const float Ac = -__expf(A_logs[d]);
  size_t base = ((size_t)(b * Lz + c * CH)) * Di + d;
  const float* Bp = Bsv + (size_t)b * Lz + c * CH;
  float P = 1.f, h = 0.f;
#pragma unroll 4
  for (int j = 0; j < CH; j++) {
    const float dl = bf2f(delta[base + (size_t)j * Di]);
    const float uu = bf2f(u[base + (size_t)j * Di]);
    const float a  = __expf(dl * Ac);
    h = a * h + dl * Bp[j] * uu;
    P *= a;
  }
  const int ci = (b * NCH + c) * Di + d;
  carryP[ci] = P;
  carryS[ci] = h;
}

__global__ __launch_bounds__(256) void scan_p2(
    const float* __restrict__ carryP, const float* __restrict__ carryS,
    float* __restrict__ hin)
{
  const int t = blockIdx.x * 256 + threadIdx.x;
  const int b = t >> 10, d = t & (Di - 1);
  float h = 0.f;
  for (int c = 0; c < NCH; c++) {
    const int ci = (b * NCH + c) * Di + d;
    hin[ci] = h;
    h = carryP[ci] * h + carryS[ci];
  }
}

__global__ __launch_bounds__(256) void scan_p3(
    const __hip_bfloat16* __restrict__ delta, __hip_bfloat16* __restrict__ uy,
    const float* __restrict__ Bsv, const float* __restrict__ Csv,
    const float* __restrict__ A_logs, const float* __restrict__ Ds,
    const float* __restrict__ hin)
{
  const int d = blockIdx.x * 256 + threadIdx.x;
  const int c = blockIdx.y, b = blockIdx.z;
  const float Ac = -__expf(A_logs[d]);
  const float Dd = Ds[d];
  size_t base = ((size_t)(b * Lz + c * CH)) * Di + d;
  const float* Bp = Bsv + (size_t)b * Lz + c * CH;
  const float* Cp = Csv + (size_t)b * Lz + c * CH;
  float h = hin[(b * NCH + c) * Di + d];
#pragma unroll 4
  for (int j = 0; j < CH; j++) {
    const size_t ix = base + (size_t)j * Di;
    const float dl = bf2f(delta[ix]);
    const float uu = bf2f(uy[ix]);
    const float a  = __expf(dl * Ac);
    h = a * h + dl * Bp[j] * uu;
    uy[ix] = __float2bfloat16(h * Cp[j] + uu * Dd);
  }
}

// ---------------------------------------------------------------------------
// LayerNorm over D=1024 + SiLU(z) gate -> bf16
// ---------------------------------------------------------------------------
__global__ __launch_bounds__(256) void ln_gate(
    const __hip_bfloat16* __restrict__ y, const __hip_bfloat16* __restrict__ z,
    const float* __restrict__ lnw, const float* __restrict__ lnb,
    __hip_bfloat16* __restrict__ yg)
{
  const int row = blockIdx.x;
  const int tid = threadIdx.x;
  const int wid = tid >> 6, lane = tid & 63;
  const short4v yv = *(const short4v*)((const short*)y + (size_t)row * Di + tid * 4);
  float v[4];
#pragma unroll
  for (int i = 0; i < 4; i++) {
    __hip_bfloat16 t;
    *(short*)&t = yv[i];
    v[i] = bf2f(t);
  }
  float s1 = v[0] + v[1] + v[2] + v[3];
  float s2 = v[0] * v[0] + v[1] * v[1] + v[2] * v[2] + v[3] * v[3];
#pragma unroll
  for (int o = 32; o > 0; o >>= 1) {
    s1 += __shfl_down(s1, o, 64);
    s2 += __shfl_down(s2, o, 64);
  }
  __shared__ float r1[4], r2[4];
  if (lane == 0) { r1[wid] = s1; r2[wid] = s2; }
  __syncthreads();
  const float t1 = r1[0] + r1[1] + r1[2] + r1[3];
  const float t2 = r2[0] + r2[1] + r2[2] + r2[3];
  const float mu = t1 * (1.f / Di);
  const float var = t2 * (1.f / Di) - mu * mu;
  const float rstd = rsqrtf(var + 1e-5f);

  const float4 wv = ((const float4*)lnw)[tid];
  const float4 bv = ((const float4*)lnb)[tid];
  const float wa[4] = {wv.x, wv.y, wv.z, wv.w};
  const float ba[4] = {bv.x, bv.y, bv.z, bv.w};
  const __hip_bfloat16* zr = z + (size_t)row * Di + tid * 4;
  __hip_bfloat16* outp = yg + (size_t)row * Di + tid * 4;
#pragma unroll
  for (int i = 0; i < 4; i++) {
    const float zv = bf2f(zr[i]);
    const float g = zv / (1.f + __expf(-zv));
    outp[i] = __float2bfloat16(((v[i] - mu) * rstd * wa[i] + ba[i]) * g);
  }
}

// ---------------------------------------------------------------------------
// Diagnostic: fill d_out (f32) with ws_size expressed in KiB (read via absmax).
// ---------------------------------------------------------------------------
__global__ __launch_bounds__(256) void fill_diag(float* __restrict__ out, int n, float val)
{
  const int i = blockIdx.x * 256 + threadIdx.x;
  if (i < n) out[i] = val;
}

// ---------------------------------------------------------------------------
extern "C" void kernel_launch(void* const* d_in, const int* in_sizes, int n_in,
                              void* d_out, int out_size, void* d_ws, size_t ws_size,
                              hipStream_t stream)
{
  const float* x      = (const float*)d_in[0];
  const float* w_in   = (const float*)d_in[1];
  const float* conv_w = (const float*)d_in[2];
  const float* conv_b = (const float*)d_in[3];
  const float* xpw    = (const float*)d_in[4];
  const float* dtw    = (const float*)d_in[5];
  const float* dtb    = (const float*)d_in[6];
  const float* A_logs = (const float*)d_in[7];
  const float* Ds     = (const float*)d_in[8];
  const float* lnw    = (const float*)d_in[9];
  const float* lnb    = (const float*)d_in[10];
  const float* w_out  = (const float*)d_in[11];
  float* outF = (float*)d_out;   // 16.7M f32 = 64 MiB

  const size_t BF16BIG  = (size_t)Mrows * Di * sizeof(__hip_bfloat16); // 32 MiB
  const size_t NEED_RUN = 69603328;  // exact ws usage below (unchanged)

  if (ws_size < NEED_RUN) {
    fill_diag<<<(out_size + 255) / 256, 256, 0, stream>>>(
        outF, out_size, (float)(ws_size >> 10));
    return;
  }

  uint8_t* ws = (uint8_t*)d_ws;
  size_t off = 0;
  auto alloc = [&](size_t bytes) { void* p = ws + off; off += (bytes + 255) & ~(size_t)255; return p; };

  // ws layout (66.4 MiB total):
  __hip_bfloat16* slotA    = (__hip_bfloat16*)alloc(BF16BIG);   // xc -> delta -> yg
  __hip_bfloat16* slotC    = (__hip_bfloat16*)alloc(BF16BIG);   // xbf -> u -> y (in-place)
  __hip_bfloat16* w_out_bf = (__hip_bfloat16*)alloc((size_t)Dm * Di * 2);
  __hip_bfloat16* xpw_bf   = (__hip_bfloat16*)alloc((size_t)66 * Di * 2);
  __hip_bfloat16* dtw_bf   = (__hip_bfloat16*)alloc((size_t)Di * 64 * 2);
  float* Bsv = (float*)alloc((size_t)Mrows * sizeof(float));
  float* Csv = (float*)alloc((size_t)Mrows * sizeof(float));

  // d_out (64 MiB f32) doubles as scratch for regions dead before stage 9:
  __hip_bfloat16* zbuf    = (__hip_bfloat16*)d_out;                        // [0,32M): z
  __hip_bfloat16* w_in_bf = (__hip_bfloat16*)((uint8_t*)d_out + 33554432); // [32M,36M)
  uint8_t* dts_region     = (uint8_t*)d_out + 37748736;                    // [36M,38M)
  float* xpj_part         = (float*)((uint8_t*)d_out + 41943040);          // [40M,57.3M)
  __hip_bfloat16* dts = (__hip_bfloat16*)dts_region;
  float* carryP = (float*)dts_region;                 // overlays dts (dead after stage 4)
  float* carryS = carryP + (size_t)Bz * NCH * Di;
  float* hin    = carryS + (size_t)Bz * NCH * Di;

  __hip_bfloat16* xbf   = slotC;   // dead after stage 1 (overwritten by u)
  __hip_bfloat16* xcbuf = slotA;
  __hip_bfloat16* ubuf  = slotC;
  __hip_bfloat16* delta = slotA;   // overwrites xc (dead after conv)
  __hip_bfloat16* yg    = slotA;   // overwrites delta (dead after scan_p3)

  // 0. convert f32 inputs -> bf16 working copies
  cvt_bf16<<<(Mrows * Di / 4 + 255) / 256, 256, 0, stream>>>(x, xbf, Mrows * Di / 4);
  cvt_weights<<<(819712 + 255) / 256, 256, 0, stream>>>(
      w_in, w_out, xpw, dtw, w_in_bf, w_out_bf, xpw_bf, dtw_bf);

  // 1. xz = x @ w_in^T -> xc (slotA), z (d_out[0,32M))  [256^2 8-phase]
  gemm256<0><<<dim3(2 * Di / 256, Mrows / 256), 512, 0, stream>>>(
      xbf, w_in_bf, Dm, 2 * Di, xcbuf, zbuf, nullptr);
  // 2. conv + silu -> u (slotC; xbf dead)
  conv_silu<<<(Mrows * Di) / 256, 256, 0, stream>>>(xcbuf, conv_w, conv_b, ubuf);
  // 3. x_proj split-K -> partials -> reduce to dts, Bs, Cs
  gemm_xproj<<<dim3(XPJ_KS, Mrows / 128), 256, 0, stream>>>(ubuf, xpw_bf, xpj_part);
  xproj_reduce<<<(Mrows * 66 + 255) / 256, 256, 0, stream>>>(xpj_part, dts, Bsv, Csv);
  // 4. delta = softplus(dts @ dtw^T + bias) -> slotA (xc dead)  [K=64, mem-bound]
  gemm128<1><<<dim3(Di / 128, Mrows / 128), 256, 0, stream>>>(
      dts, dtw_bf, 64, Di, delta, nullptr, nullptr, dtb);
  // 5-7. chunked scan; y written in-place over u
  scan_p1<<<dim3(Di / 256, NCH, Bz), 256, 0, stream>>>(delta, ubuf, Bsv, A_logs, carryP, carryS);
  scan_p2<<<(Bz * Di) / 256, 256, 0, stream>>>(carryP, carryS, hin);
  scan_p3<<<dim3(Di / 256, NCH, Bz), 256, 0, stream>>>(delta, ubuf, Bsv, Csv, A_logs, Ds, hin);
  // 8. layernorm + silu(z) gate -> yg (slotA; delta dead)
  ln_gate<<<Mrows, 256, 0, stream>>>(ubuf, zbuf, lnw, lnb, yg);
  // 9. out = yg @ w_out^T -> d_out f32 (overwrites all d_out scratch — dead)
  gemm256<1><<<dim3(Dm / 256, Mrows / 256), 512, 0, stream>>>(
      yg, w_out_bf, Di, Dm, nullptr, nullptr, outF);
}

// Round 2
// 365.703 us; speedup vs baseline: 1.1228x; 1.0402x over previous
//
#include <hip/hip_runtime.h>
#include <hip/hip_bf16.h>
#include <cstdint>
#include <cstddef>

typedef short short8 __attribute__((ext_vector_type(8)));
typedef short short4v __attribute__((ext_vector_type(4)));
typedef float floatx4 __attribute__((ext_vector_type(4)));

constexpr int Bz = 4;
constexpr int Lz = 4096;
constexpr int Dm = 1024;       // d_model
constexpr int Di = 1024;       // d_inner
constexpr int Mrows = Bz * Lz; // 16384
constexpr int CH  = 128;       // scan chunk length
constexpr int NCH = Lz / CH;   // 32
constexpr int XPJ_KS = 4;      // x_proj split-K factor

__device__ __forceinline__ void load16(const void* g, void* l) {
  __builtin_amdgcn_global_load_lds((__attribute__((address_space(1))) void*)g,
                                   (__attribute__((address_space(3))) void*)l,
                                   16, 0, 0);
}

__device__ __forceinline__ float bf2f(const __hip_bfloat16 v) { return __bfloat162float(v); }
__device__ __forceinline__ short f2bfs(float v) {
  __hip_bfloat16 h = __float2bfloat16(v);
  return *(short*)&h;
}

// ---------------------------------------------------------------------------
// f32 -> bf16 conversion, 4 elements/thread.
// ---------------------------------------------------------------------------
__global__ __launch_bounds__(256) void cvt_bf16(const float* __restrict__ in,
                                                __hip_bfloat16* __restrict__ out, int n4)
{
  const int i = blockIdx.x * 256 + threadIdx.x;
  if (i >= n4) return;
  const float4 v = ((const float4*)in)[i];
  short4v s;
  s[0] = f2bfs(v.x); s[1] = f2bfs(v.y); s[2] = f2bfs(v.z); s[3] = f2bfs(v.w);
  ((short4v*)out)[i] = s;
}

// All 4 weight matrices in one launch. Ranges in units of 4 floats.
__global__ __launch_bounds__(256) void cvt_weights(
    const float* __restrict__ w_in, const float* __restrict__ w_out,
    const float* __restrict__ xpw, const float* __restrict__ dtw,
    __hip_bfloat16* __restrict__ w_in_bf, __hip_bfloat16* __restrict__ w_out_bf,
    __hip_bfloat16* __restrict__ xpw_bf, __hip_bfloat16* __restrict__ dtw_bf)
{
  const int i = blockIdx.x * 256 + threadIdx.x;
  const float* src; __hip_bfloat16* dst; int j;
  if (i < 524288)      { src = w_in;  dst = w_in_bf;  j = i; }
  else if (i < 786432) { src = w_out; dst = w_out_bf; j = i - 524288; }
  else if (i < 803328) { src = xpw;   dst = xpw_bf;   j = i - 786432; }
  else if (i < 819712) { src = dtw;   dst = dtw_bf;   j = i - 803328; }
  else return;
  const float4 v = ((const float4*)src)[j];
  short4v s;
  s[0] = f2bfs(v.x); s[1] = f2bfs(v.y); s[2] = f2bfs(v.z); s[3] = f2bfs(v.w);
  ((short4v*)dst)[j] = s;
}

// ---------------------------------------------------------------------------
// 128x128 MFMA GEMM (m97-class structure). Retained ONLY for the K=64
// delta GEMM (EPI 1), which is memory-bound.
// ---------------------------------------------------------------------------
template <int EPI>
__global__ __launch_bounds__(256) void gemm128(
    const __hip_bfloat16* __restrict__ A,
    const __hip_bfloat16* __restrict__ W,
    int K, int N,
    __hip_bfloat16* __restrict__ outb0,
    __hip_bfloat16* __restrict__ outb1,
    float* __restrict__ outf,
    const float* __restrict__ biasf)
{
  constexpr int BK = 32;
  constexpr int GY = 16;
  __shared__ short sA[128 * BK];
  __shared__ short sB[128 * BK];
  const int tid  = threadIdx.x;
  const int wid  = tid >> 6;
  const int lane = tid & 63;

  const int gx  = gridDim.x;
  const int id  = blockIdx.y * gx + blockIdx.x;
  const int seg = gx * GY;
  const int bx  = (id % seg) / GY;
  const int by  = (id / seg) * GY + (id % GY);

  const int m0 = by * 128;
  const int n0 = bx * 128;
  const int wm = (wid & 1) * 64;
  const int wn = (wid >> 1) * 64;

  floatx4 acc[4][4];
#pragma unroll
  for (int i = 0; i < 4; i++)
#pragma unroll
    for (int j = 0; j < 4; j++) acc[i][j] = (floatx4){0.f, 0.f, 0.f, 0.f};

  const short* Ag = (const short*)A + (size_t)(m0 + (tid >> 2)) * K + (tid & 3) * 8;
  const short* Bg = (const short*)W + (size_t)(n0 + (tid >> 2)) * K + (tid & 3) * 8;
  short* sAd = &sA[tid * 8];
  short* sBd = &sB[tid * 8];
  const size_t rstep = (size_t)64 * K;
  const int fr = lane & 15, fq = lane >> 4;

  for (int kb = 0; kb < K; kb += BK) {
    load16(Ag, sAd);
    load16(Ag + rstep, sAd + 2048);
    load16(Bg, sBd);
    load16(Bg + rstep, sBd + 2048);
    Ag += BK; Bg += BK;
    __syncthreads();

    short8 av[4], bv[4];
#pragma unroll
    for (int mt = 0; mt < 4; mt++) av[mt] = *(const short8*)&sA[(wm + mt * 16 + fr) * BK + fq * 8];
#pragma unroll
    for (int nt = 0; nt < 4; nt++) bv[nt] = *(const short8*)&sB[(wn + nt * 16 + fr) * BK + fq * 8];
#pragma unroll
    for (int mt = 0; mt < 4; mt++)
#pragma unroll
      for (int nt = 0; nt < 4; nt++)
        acc[mt][nt] = __builtin_amdgcn_mfma_f32_16x16x32_bf16(av[mt], bv[nt], acc[mt][nt], 0, 0, 0);
    __syncthreads();
  }

#pragma unroll
  for (int mt = 0; mt < 4; mt++) {
#pragma unroll
    for (int nt = 0; nt < 4; nt++) {
#pragma unroll
      for (int r = 0; r < 4; r++) {
        const int gm = m0 + wm + mt * 16 + fq * 4 + r;
        const int gn = n0 + wn + nt * 16 + fr;
        float v = acc[mt][nt][r];
        if constexpr (EPI == 0) {
          if (gn < 1024) outb0[(size_t)gm * 1024 + gn] = __float2bfloat16(v);
          else           outb1[(size_t)gm * 1024 + (gn - 1024)] = __float2bfloat16(v);
        } else if constexpr (EPI == 1) {
          v += biasf[gn];
          v = (v > 15.f) ? v : __logf(1.f + __expf(v));
          outb0[(size_t)gm * N + gn] = __float2bfloat16(v);
        } else {
          outf[(size_t)gm * N + gn] = v;
        }
      }
    }
  }
}

// ---------------------------------------------------------------------------
// 256x256 8-phase MFMA GEMM. C[M,N] = A[M,K] (bf16 rm) * W[N,K]^T (bf16 rm).
// 512 threads = 8 waves (2M x 4N), per-wave 128x64 output. BK=64.
// LDS 128 KiB: A[2buf][2half][16 subtiles(16x32)x1024B], B same at +64KB.
// Swizzle: within 1024B subtile, byte ^= ((row&8)?32:0). global_load_lds
// writes LINEAR LDS; the global SOURCE address is inverse-swizzled (rule #21).
//
// ROUND-2 CHANGES vs round 1 (measured 874 TF, MfmaUtil 35%):
//  (a) barriers/waits were asm volatile with "memory" clobber -> backend
//      inserted conservative vmcnt(0) drains, defeating the counted-vmcnt
//      pipeline (T4). Now: __builtin_amdgcn_s_barrier() + bare asm waitcnt
//      + sched_barrier(0) after each wait (rule #18), per the verified m201
//      template.
//  (b) bijective XCD swizzle (nwg%8==0): each XCD owns a contiguous by-range
//      -> A-panels XCD-exclusive, cuts EA re-fetch (was 135 MB/dispatch).
//
// Hazard proof (no clobbers needed): every wave executes lgkmcnt(0) BEFORE
// the phase-end barrier, so all its ds_reads of buf[cur] are complete before
// any wave issues the next phase's stage into buf[cur]. vmcnt(6) at ph4
// forces K-tile t+1 fully resident before its first read.
// ---------------------------------------------------------------------------
__device__ __forceinline__ void wait_lgkm0() {
  asm volatile("s_waitcnt lgkmcnt(0)");
  __builtin_amdgcn_sched_barrier(0);
}

template <int EPI>
__device__ __forceinline__ void cluster_mfma(int MQ, floatx4 (&acc)[8][4],
                                             const short8 (&av)[8][2],
                                             const short8 (&bv)[4][2])
{
  __builtin_amdgcn_s_setprio(1);
#pragma unroll
  for (int j = 0; j < 2; j++)
#pragma unroll
    for (int nf = 0; nf < 4; nf++)
#pragma unroll
      for (int ks = 0; ks < 2; ks++)
        acc[2 * MQ + j][nf] = __builtin_amdgcn_mfma_f32_16x16x32_bf16(
            av[2 * MQ + j][ks], bv[nf][ks], acc[2 * MQ + j][nf], 0, 0, 0);
  __builtin_amdgcn_s_setprio(0);
}

template <int EPI>
__global__ __launch_bounds__(512, 2) void gemm256(
    const __hip_bfloat16* __restrict__ A,
    const __hip_bfloat16* __restrict__ W,
    int K, int N,
    __hip_bfloat16* __restrict__ outb0,
    __hip_bfloat16* __restrict__ outb1,
    float* __restrict__ outf)
{
  __shared__ alignas(16) char lds[131072];
  const int tid  = threadIdx.x;
  const int wid  = tid >> 6;
  const int lane = tid & 63;
  const int wm = wid >> 2;      // 0..1
  const int wn = wid & 3;       // 0..3
  const int fr = lane & 15, fq = lane >> 4;

  // Bijective XCD swizzle (nwg % 8 == 0 for all launches here). x-fastest
  // decomposition: each XCD owns a contiguous by-range -> A-panel exclusive.
  const int gx   = gridDim.x;
  const int nwg  = gx * gridDim.y;
  const int orig = blockIdx.y * gx + blockIdx.x;
  const int swz  = (orig & 7) * (nwg >> 3) + (orig >> 3);
  const int bx   = swz % gx;
  const int by   = swz / gx;
  const int m0 = by * 256;
  const int n0 = bx * 256;
  const size_t K2 = (size_t)K * 2;   // row bytes

  // Staging: thread chunk i covers LDS bytes p=(i*512+tid)*16 of a 16KB half.
  // Inverse-swizzle to find which global element belongs at linear byte p.
  int rowo[2], colo[2];
#pragma unroll
  for (int i = 0; i < 2; i++) {
    const int p = i * 8192 + tid * 16;
    const int s = p >> 10;           // subtile 0..15 (rb*2+cb)
    const int r = (p >> 6) & 15;     // row within subtile
    rowo[i] = (s >> 1) * 16 + r;                                  // 0..127
    colo[i] = (s & 1) * 64 + ((p & 63) ^ (((r >> 3) & 1) << 5));  // byte 0..127
  }
  const char* Ab = (const char*)A + (size_t)m0 * K2;
  const char* Bb = (const char*)W + (size_t)n0 * K2;
  char* lbase = (char*)lds;

#define STAGE_A(c, h, kt) do {                                                          \
    load16(Ab + (size_t)((h) * 128 + rowo[0]) * K2 + (size_t)(kt) * 128 + colo[0],      \
           lbase + (c) * 32768 + (h) * 16384 + tid * 16);                               \
    load16(Ab + (size_t)((h) * 128 + rowo[1]) * K2 + (size_t)(kt) * 128 + colo[1],      \
           lbase + (c) * 32768 + (h) * 16384 + 8192 + tid * 16);                        \
  } while (0)
#define STAGE_B(c, h, kt) do {                                                          \
    load16(Bb + (size_t)((h) * 128 + rowo[0]) * K2 + (size_t)(kt) * 128 + colo[0],      \
           lbase + 65536 + (c) * 32768 + (h) * 16384 + tid * 16);                       \
    load16(Bb + (size_t)((h) * 128 + rowo[1]) * K2 + (size_t)(kt) * 128 + colo[1],      \
           lbase + 65536 + (c) * 32768 + (h) * 16384 + 8192 + tid * 16);                \
  } while (0)

  // Fragment read offset within its 1024B subtile (swizzled, 16B aligned).
  const int foff = (fr * 64 + fq * 16) ^ (((fr >> 3) & 1) << 5);

  floatx4 acc[8][4];
#pragma unroll
  for (int i = 0; i < 8; i++)
#pragma unroll
    for (int j = 0; j < 4; j++) acc[i][j] = (floatx4){0.f, 0.f, 0.f, 0.f};

  // Prologue: K0 all 4 halves, then K1 {B0,B1,A0}. vmcnt(6) => K0 landed.
  STAGE_A(0, 0, 0); STAGE_A(0, 1, 0); STAGE_B(0, 0, 0); STAGE_B(0, 1, 0);
  STAGE_B(1, 0, 1); STAGE_B(1, 1, 1); STAGE_A(1, 0, 1);
  asm volatile("s_waitcnt vmcnt(6)");
  __builtin_amdgcn_sched_barrier(0);
  __builtin_amdgcn_s_barrier();

  const int NT = K >> 6;
  short8 av[8][2], bv[4][2];
#pragma unroll 2
  for (int t = 0; t < NT; ++t) {
    const int cur = t & 1, nxt = cur ^ 1;
    const char* la = lbase + cur * 32768 + wm * 16384 + foff;
    const char* lb = lbase + 65536 + cur * 32768 + (wn >> 1) * 16384 + (wn & 1) * 8192 + foff;

    // ---------------- phase 1: all B frags + av[0,1]; stage A1(t+1)->nxt
#pragma unroll
    for (int nf = 0; nf < 4; nf++)
#pragma unroll
      for (int ks = 0; ks < 2; ks++)
        bv[nf][ks] = *(const short8*)(lb + (nf * 2 + ks) * 1024);
#pragma unroll
    for (int mf = 0; mf < 2; mf++)
#pragma unroll
      for (int ks = 0; ks < 2; ks++)
        av[mf][ks] = *(const short8*)(la + (mf * 2 + ks) * 1024);
    if (t + 1 < NT) STAGE_A(nxt, 1, t + 1);
    __builtin_amdgcn_s_barrier();
    wait_lgkm0();
    cluster_mfma<EPI>(0, acc, av, bv);
    __builtin_amdgcn_s_barrier();

    // ---------------- phase 2: av[2,3]; stage B0(t+2)->cur (B reads done ph1)
#pragma unroll
    for (int mf = 2; mf < 4; mf++)
#pragma unroll
      for (int ks = 0; ks < 2; ks++)
        av[mf][ks] = *(const short8*)(la + (mf * 2 + ks) * 1024);
    if (t + 2 < NT) STAGE_B(cur, 0, t + 2);
    __builtin_amdgcn_s_barrier();
    wait_lgkm0();
    cluster_mfma<EPI>(1, acc, av, bv);
    __builtin_amdgcn_s_barrier();

    // ---------------- phase 3: av[4..7]; stage B1(t+2)->cur
#pragma unroll
    for (int mf = 4; mf < 8; mf++)
#pragma unroll
      for (int ks = 0; ks < 2; ks++)
        av[mf][ks] = *(const short8*)(la + (mf * 2 + ks) * 1024);
    if (t + 2 < NT) STAGE_B(cur, 1, t + 2);
    __builtin_amdgcn_s_barrier();
    wait_lgkm0();
    cluster_mfma<EPI>(2, acc, av, bv);
    __builtin_amdgcn_s_barrier();

    // ---------------- phase 4: no reads; stage A0(t+2)->cur (A reads done ph3)
    if (t + 2 < NT) STAGE_A(cur, 0, t + 2);
    __builtin_amdgcn_s_barrier();
    cluster_mfma<EPI>(3, acc, av, bv);
    // counted vmcnt once per K-tile: 3 newest half-tiles (6 loads) in flight.
    if (t < NT - 2) {
      asm volatile("s_waitcnt vmcnt(6)");
      __builtin_amdgcn_sched_barrier(0);
      __builtin_amdgcn_s_barrier();
    } else if (t == NT - 2) {
      asm volatile("s_waitcnt vmcnt(0)");
      __builtin_amdgcn_sched_barrier(0);
      __builtin_amdgcn_s_barrier();
    } // t == NT-1: fall through to epilogue
  }
#undef STAGE_A
#undef STAGE_B

#pragma unroll
  for (int mf = 0; mf < 8; mf++) {
#pragma unroll
    for (int nf = 0; nf < 4; nf++) {
#pragma unroll
      for (int r = 0; r < 4; r++) {
        const int gm = m0 + wm * 128 + mf * 16 + fq * 4 + r;
        const int gn = n0 + wn * 64 + nf * 16 + fr;
        const float v = acc[mf][nf][r];
        if constexpr (EPI == 0) {
          if (gn < 1024) outb0[(size_t)gm * 1024 + gn] = __float2bfloat16(v);
          else           outb1[(size_t)gm * 1024 + (gn - 1024)] = __float2bfloat16(v);
        } else {
          outf[(size_t)gm * N + gn] = v;
        }
      }
    }
  }
}

// ---------------------------------------------------------------------------
// x_proj GEMM, split-K x4: partial[kc][M,66] = u[M, kc-chunk] * xpw[66, kc-chunk]^T
// ---------------------------------------------------------------------------
__global__ __launch_bounds__(256) void gemm_xproj(
    const __hip_bfloat16* __restrict__ A,
    const __hip_bfloat16* __restrict__ W,
    float* __restrict__ part)
{
  constexpr int K = 1024, BK = 32, KC = K / XPJ_KS; // 256
  __shared__ short sA[128 * BK];
  __shared__ short sB[80 * BK];
  const int tid = threadIdx.x;
  const int wid = tid >> 6, lane = tid & 63;
  const int kc = blockIdx.x;
  const int m0 = blockIdx.y * 128;

  floatx4 acc[2][5];
#pragma unroll
  for (int i = 0; i < 2; i++)
#pragma unroll
    for (int j = 0; j < 5; j++) acc[i][j] = (floatx4){0.f, 0.f, 0.f, 0.f};

  const short* Ag = (const short*)A + (size_t)(m0 + (tid >> 2)) * K + kc * KC + (tid & 3) * 8;
  const int brow2 = 64 + (tid >> 2);
  const int brow2c = brow2 > 65 ? 65 : brow2;
  const short* Bg  = (const short*)W + (size_t)(tid >> 2) * K + kc * KC + (tid & 3) * 8;
  const short* Bg2 = (const short*)W + (size_t)brow2c * K + kc * KC + (tid & 3) * 8;
  const size_t rstep = (size_t)64 * K;
  const int fr = lane & 15, fq = lane >> 4;

  for (int kb = 0; kb < KC; kb += BK) {
    load16(Ag, &sA[tid * 8]);
    load16(Ag + rstep, &sA[2048 + tid * 8]);
    load16(Bg, &sB[tid * 8]);
    if (tid < 64) load16(Bg2, &sB[2048 + tid * 8]);
    Ag += BK; Bg += BK; Bg2 += BK;
    __syncthreads();

    short8 av[2], bv[5];
#pragma unroll
    for (int mt = 0; mt < 2; mt++) av[mt] = *(const short8*)&sA[(wid * 32 + mt * 16 + fr) * BK + fq * 8];
#pragma unroll
    for (int nt = 0; nt < 5; nt++) bv[nt] = *(const short8*)&sB[(nt * 16 + fr) * BK + fq * 8];
#pragma unroll
    for (int mt = 0; mt < 2; mt++)
#pragma unroll
      for (int nt = 0; nt < 5; nt++)
        acc[mt][nt] = __builtin_amdgcn_mfma_f32_16x16x32_bf16(av[mt], bv[nt], acc[mt][nt], 0, 0, 0);
    __syncthreads();
  }

  float* pp = part + (size_t)kc * Mrows * 66;
#pragma unroll
  for (int mt = 0; mt < 2; mt++) {
#pragma unroll
    for (int nt = 0; nt < 5; nt++) {
#pragma unroll
      for (int r = 0; r < 4; r++) {
        const int gm = m0 + wid * 32 + mt * 16 + fq * 4 + r;
        const int gn = nt * 16 + fr;
        if (gn < 66) pp[(size_t)gm * 66 + gn] = acc[mt][nt][r];
      }
    }
  }
}

__global__ __launch_bounds__(256) void xproj_reduce(
    const float* __restrict__ part,
    __hip_bfloat16* __restrict__ dts,
    float* __restrict__ Bs, float* __restrict__ Cs)
{
  const int i = blockIdx.x * 256 + threadIdx.x;
  if (i >= Mrows * 66) return;
  const int gm = i / 66, gn = i - gm * 66;
  float s = part[i] + part[i + (size_t)Mrows * 66]
          + part[i + (size_t)2 * Mrows * 66] + part[i + (size_t)3 * Mrows * 66];
  if (gn < 64)       dts[(size_t)gm * 64 + gn] = __float2bfloat16(s);
  else if (gn == 64) Bs[gm] = s;
  else               Cs[gm] = s;
}

// ---------------------------------------------------------------------------
// Causal depthwise conv (k=2) + bias + SiLU.  bf16 data, f32 params.
// ---------------------------------------------------------------------------
__global__ __launch_bounds__(256) void conv_silu(
    const __hip_bfloat16* __restrict__ xc, const float* __restrict__ cw,
    const float* __restrict__ cb, __hip_bfloat16* __restrict__ u)
{
  const size_t idx = (size_t)blockIdx.x * 256 + threadIdx.x;
  const int d = (int)(idx & (Di - 1));
  const int l = (int)((idx >> 10) & (Lz - 1));
  const float w0 = cw[2 * d], w1 = cw[2 * d + 1];
  const float prev = (l > 0) ? bf2f(xc[idx - Di]) : 0.f;
  const float v = prev * w0 + bf2f(xc[idx]) * w1 + cb[d];
  const float s = v / (1.f + __expf(-v));
  u[idx] = __float2bfloat16(s);
}

// ---------------------------------------------------------------------------
// Chunked scan, D_STATE=1:  h[l] = exp(delta*A)*h[l-1] + delta*Bs*u
// ---------------------------------------------------------------------------
__global__ __launch_bounds__(256) void scan_p1(
    const __hip_bfloat16* __restrict__ delta, const __hip_bfloat16* __restrict__ u,
    const float* __restrict__ Bsv, const float* __restrict__ A_logs,
    float* __restrict__ carryP, float* __restrict__ carryS)
{
  const int d = blockIdx.x * 256 + threadIdx.x;
  const int c = blockIdx.y, b = blockIdx.z;
  const float Ac = -__expf(A_logs[d]);
  size_t base = ((size_t)(b * Lz + c * CH)) * Di + d;
  const float* Bp = Bsv + (size_t)b * Lz + c * CH;
  float P = 1.f, h = 0.f;
#pragma unroll 4
  for (int j = 0; j < CH; j++) {
    const float dl = bf2f(delta[base + (size_t)j * Di]);
    const float uu = bf2f(u[base + (size_t)j * Di]);
    const float a  = __expf(dl * Ac);
    h = a * h + dl * Bp[j] * uu;
    P *= a;
  }
  const int ci = (b * NCH + c) * Di + d;
  carryP[ci] = P;
  carryS[ci] = h;
}

__global__ __launch_bounds__(256) void scan_p2(
    const float* __restrict__ carryP, const float* __restrict__ carryS,
    float* __restrict__ hin)
{
  const int t = blockIdx.x * 256 + threadIdx.x;
  const int b = t >> 10, d = t & (Di - 1);
  float h = 0.f;
  for (int c = 0; c < NCH; c++) {
    const int ci = (b * NCH + c) * Di + d;
    hin[ci] = h;
    h = carryP[ci] * h + carryS[ci];
  }
}

__global__ __launch_bounds__(256) void scan_p3(
    const __hip_bfloat16* __restrict__ delta, __hip_bfloat16* __restrict__ uy,
    const float* __restrict__ Bsv, const float* __restrict__ Csv,
    const float* __restrict__ A_logs, const float* __restrict__ Ds,
    const float* __restrict__ hin)
{
  const int d = blockIdx.x * 256 + threadIdx.x;
  const int c = blockIdx.y, b = blockIdx.z;
  const float Ac = -__expf(A_logs[d]);
  const float Dd = Ds[d];
  size_t base = ((size_t)(b * Lz + c * CH)) * Di + d;
  const float* Bp = Bsv + (size_t)b * Lz + c * CH;
  const float* Cp = Csv + (size_t)b * Lz + c * CH;
  float h = hin[(b * NCH + c) * Di + d];
#pragma unroll 4
  for (int j = 0; j < CH; j++) {
    const size_t ix = base + (size_t)j * Di;
    const float dl = bf2f(delta[ix]);
    const float uu = bf2f(uy[ix]);
    const float a  = __expf(dl * Ac);
    h = a * h + dl * Bp[j] * uu;
    uy[ix] = __float2bfloat16(h * Cp[j] + uu * Dd);
  }
}

// ---------------------------------------------------------------------------
// LayerNorm over D=1024 + SiLU(z) gate -> bf16
// ---------------------------------------------------------------------------
__global__ __launch_bounds__(256) void ln_gate(
    const __hip_bfloat16* __restrict__ y, const __hip_bfloat16* __restrict__ z,
    const float* __restrict__ lnw, const float* __restrict__ lnb,
    __hip_bfloat16* __restrict__ yg)
{
  const int row = blockIdx.x;
  const int tid = threadIdx.x;
  const int wid = tid >> 6, lane = tid & 63;
  const short4v yv = *(const short4v*)((const short*)y + (size_t)row * Di + tid * 4);
  float v[4];
#pragma unroll
  for (int i = 0; i < 4; i++) {
    __hip_bfloat16 t;
    *(short*)&t = yv[i];
    v[i] = bf2f(t);
  }
  float s1 = v[0] + v[1] + v[2] + v[3];
  float s2 = v[0] * v[0] + v[1] * v[1] + v[2] * v[2] + v[3] * v[3];
#pragma unroll
  for (int o = 32; o > 0; o >>= 1) {
    s1 += __shfl_down(s1, o, 64);
    s2 += __shfl_down(s2, o, 64);
  }
  __shared__ float r1[4], r2[4];
  if (lane == 0) { r1[wid] = s1; r2[wid] = s2; }
  __syncthreads();
  const float t1 = r1[0] + r1[1] + r1[2] + r1[3];
  const float t2 = r2[0] + r2[1] + r2[2] + r2[3];
  const float mu = t1 * (1.f / Di);
  const float var = t2 * (1.f / Di) - mu * mu;
  const float rstd = rsqrtf(var + 1e-5f);

  const float4 wv = ((const float4*)lnw)[tid];
  const float4 bv = ((const float4*)lnb)[tid];
  const float wa[4] = {wv.x, wv.y, wv.z, wv.w};
  const float ba[4] = {bv.x, bv.y, bv.z, bv.w};
  const __hip_bfloat16* zr = z + (size_t)row * Di + tid * 4;
  __hip_bfloat16* outp = yg + (size_t)row * Di + tid * 4;
#pragma unroll
  for (int i = 0; i < 4; i++) {
    const float zv = bf2f(zr[i]);
    const float g = zv / (1.f + __expf(-zv));
    outp[i] = __float2bfloat16(((v[i] - mu) * rstd * wa[i] + ba[i]) * g);
  }
}

// ---------------------------------------------------------------------------
// Diagnostic: fill d_out (f32) with ws_size expressed in KiB (read via absmax).
// ---------------------------------------------------------------------------
__global__ __launch_bounds__(256) void fill_diag(float* __restrict__ out, int n, float val)
{
  const int i = blockIdx.x * 256 + threadIdx.x;
  if (i < n) out[i] = val;
}

// ---------------------------------------------------------------------------
extern "C" void kernel_launch(void* const* d_in, const int* in_sizes, int n_in,
                              void* d_out, int out_size, void* d_ws, size_t ws_size,
                              hipStream_t stream)
{
  const float* x      = (const float*)d_in[0];
  const float* w_in   = (const float*)d_in[1];
  const float* conv_w = (const float*)d_in[2];
  const float* conv_b = (const float*)d_in[3];
  const float* xpw    = (const float*)d_in[4];
  const float* dtw    = (const float*)d_in[5];
  const float* dtb    = (const float*)d_in[6];
  const float* A_logs = (const float*)d_in[7];
  const float* Ds     = (const float*)d_in[8];
  const float* lnw    = (const float*)d_in[9];
  const float* lnb    = (const float*)d_in[10];
  const float* w_out  = (const float*)d_in[11];
  float* outF = (float*)d_out;   // 16.7M f32 = 64 MiB

  const size_t BF16BIG  = (size_t)Mrows * Di * sizeof(__hip_bfloat16); // 32 MiB
  const size_t NEED_RUN = 69603328;  // exact ws usage below (unchanged)

  if (ws_size < NEED_RUN) {
    fill_diag<<<(out_size + 255) / 256, 256, 0, stream>>>(
        outF, out_size, (float)(ws_size >> 10));
    return;
  }

  uint8_t* ws = (uint8_t*)d_ws;
  size_t off = 0;
  auto alloc = [&](size_t bytes) { void* p = ws + off; off += (bytes + 255) & ~(size_t)255; return p; };

  // ws layout (66.4 MiB total):
  __hip_bfloat16* slotA    = (__hip_bfloat16*)alloc(BF16BIG);   // xc -> delta -> yg
  __hip_bfloat16* slotC    = (__hip_bfloat16*)alloc(BF16BIG);   // xbf -> u -> y (in-place)
  __hip_bfloat16* w_out_bf = (__hip_bfloat16*)alloc((size_t)Dm * Di * 2);
  __hip_bfloat16* xpw_bf   = (__hip_bfloat16*)alloc((size_t)66 * Di * 2);
  __hip_bfloat16* dtw_bf   = (__hip_bfloat16*)alloc((size_t)Di * 64 * 2);
  float* Bsv = (float*)alloc((size_t)Mrows * sizeof(float));
  float* Csv = (float*)alloc((size_t)Mrows * sizeof(float));

  // d_out (64 MiB f32) doubles as scratch for regions dead before stage 9:
  __hip_bfloat16* zbuf    = (__hip_bfloat16*)d_out;                        // [0,32M): z
  __hip_bfloat16* w_in_bf = (__hip_bfloat16*)((uint8_t*)d_out + 33554432); // [32M,36M)
  uint8_t* dts_region     = (uint8_t*)d_out + 37748736;                    // [36M,38M)
  float* xpj_part         = (float*)((uint8_t*)d_out + 41943040);          // [40M,57.3M)
  __hip_bfloat16* dts = (__hip_bfloat16*)dts_region;
  float* carryP = (float*)dts_region;                 // overlays dts (dead after stage 4)
  float* carryS = carryP + (size_t)Bz * NCH * Di;
  float* hin    = carryS + (size_t)Bz * NCH * Di;

  __hip_bfloat16* xbf   = slotC;   // dead after stage 1 (overwritten by u)
  __hip_bfloat16* xcbuf = slotA;
  __hip_bfloat16* ubuf  = slotC;
  __hip_bfloat16* delta = slotA;   // overwrites xc (dead after conv)
  __hip_bfloat16* yg    = slotA;   // overwrites delta (dead after scan_p3)

  // 0. convert f32 inputs -> bf16 working copies
  cvt_bf16<<<(Mrows * Di / 4 + 255) / 256, 256, 0, stream>>>(x, xbf, Mrows * Di / 4);
  cvt_weights<<<(819712 + 255) / 256, 256, 0, stream>>>(
      w_in, w_out, xpw, dtw, w_in_bf, w_out_bf, xpw_bf, dtw_bf);

  // 1. xz = x @ w_in^T -> xc (slotA), z (d_out[0,32M))  [256^2 8-phase]
  gemm256<0><<<dim3(2 * Di / 256, Mrows / 256), 512, 0, stream>>>(
      xbf, w_in_bf, Dm, 2 * Di, xcbuf, zbuf, nullptr);
  // 2. conv + silu -> u (slotC; xbf dead)
  conv_silu<<<(Mrows * Di) / 256, 256, 0, stream>>>(xcbuf, conv_w, conv_b, ubuf);
  // 3. x_proj split-K -> partials -> reduce to dts, Bs, Cs
  gemm_xproj<<<dim3(XPJ_KS, Mrows / 128), 256, 0, stream>>>(ubuf, xpw_bf, xpj_part);
  xproj_reduce<<<(Mrows * 66 + 255) / 256, 256, 0, stream>>>(xpj_part, dts, Bsv, Csv);
  // 4. delta = softplus(dts @ dtw^T + bias) -> slotA (xc dead)  [K=64, mem-bound]
  gemm128<1><<<dim3(Di / 128, Mrows / 128), 256, 0, stream>>>(
      dts, dtw_bf, 64, Di, delta, nullptr, nullptr, dtb);
  // 5-7. chunked scan; y written in-place over u
  scan_p1<<<dim3(Di / 256, NCH, Bz), 256, 0, stream>>>(delta, ubuf, Bsv, A_logs, carryP, carryS);
  scan_p2<<<(Bz * Di) / 256, 256, 0, stream>>>(carryP, carryS, hin);
  scan_p3<<<dim3(Di / 256, NCH, Bz), 256, 0, stream>>>(delta, ubuf, Bsv, Csv, A_logs, Ds, hin);
  // 8. layernorm + silu(z) gate -> yg (slotA; delta dead)
  ln_gate<<<Mrows, 256, 0, stream>>>(ubuf, zbuf, lnw, lnb, yg);
  // 9. out = yg @ w_out^T -> d_out f32 (overwrites all d_out scratch — dead)
  gemm256<1><<<dim3(Dm / 256, Mrows / 256), 512, 0, stream>>>(
      yg, w_out_bf, Di, Dm, nullptr, nullptr, outF);
}

// Round 6
// 353.560 us; speedup vs baseline: 1.1614x; 1.0343x over previous
//
#include <hip/hip_runtime.h>
#include <hip/hip_bf16.h>
#include <cstdint>
#include <cstddef>

typedef short short8 __attribute__((ext_vector_type(8)));
typedef short short4v __attribute__((ext_vector_type(4)));
typedef float floatx4 __attribute__((ext_vector_type(4)));

constexpr int Bz = 4;
constexpr int Lz = 4096;
constexpr int Dm = 1024;       // d_model
constexpr int Di = 1024;       // d_inner
constexpr int Mrows = Bz * Lz; // 16384
constexpr int CH  = 32;        // scan chunk length (was 128: more wg = more latency hiding)
constexpr int NCH = Lz / CH;   // 128
constexpr int XPJ_KS = 4;      // x_proj split-K factor

__device__ __forceinline__ void load16(const void* g, void* l) {
  __builtin_amdgcn_global_load_lds((__attribute__((address_space(1))) void*)g,
                                   (__attribute__((address_space(3))) void*)l,
                                   16, 0, 0);
}

__device__ __forceinline__ float bf2f(const __hip_bfloat16 v) { return __bfloat162float(v); }
__device__ __forceinline__ short f2bfs(float v) {
  __hip_bfloat16 h = __float2bfloat16(v);
  return *(short*)&h;
}

// ---------------------------------------------------------------------------
// All f32->bf16 conversions (x + 4 weight matrices) in ONE launch.
// Ranges in units of 4 floats.
// ---------------------------------------------------------------------------
__global__ __launch_bounds__(256) void cvt_all(
    const float* __restrict__ x, const float* __restrict__ w_in,
    const float* __restrict__ w_out, const float* __restrict__ xpw,
    const float* __restrict__ dtw,
    __hip_bfloat16* __restrict__ xbf, __hip_bfloat16* __restrict__ w_in_bf,
    __hip_bfloat16* __restrict__ w_out_bf, __hip_bfloat16* __restrict__ xpw_bf,
    __hip_bfloat16* __restrict__ dtw_bf)
{
  const int i = blockIdx.x * 256 + threadIdx.x;
  const float* src; __hip_bfloat16* dst; int j;
  if (i < 4194304)      { src = x;     dst = xbf;      j = i; }            // 16M elems
  else if (i < 4718592) { src = w_in;  dst = w_in_bf;  j = i - 4194304; }  // 2M
  else if (i < 4980736) { src = w_out; dst = w_out_bf; j = i - 4718592; }  // 1M
  else if (i < 4997632) { src = xpw;   dst = xpw_bf;   j = i - 4980736; }  // 66K
  else if (i < 5014016) { src = dtw;   dst = dtw_bf;   j = i - 4997632; }  // 64K
  else return;
  const float4 v = ((const float4*)src)[j];
  short4v s;
  s[0] = f2bfs(v.x); s[1] = f2bfs(v.y); s[2] = f2bfs(v.z); s[3] = f2bfs(v.w);
  ((short4v*)dst)[j] = s;
}

// ---------------------------------------------------------------------------
// 128x128 MFMA GEMM (m97-class structure). Retained ONLY for the K=64
// delta GEMM (EPI 1), which is memory-bound.
// ---------------------------------------------------------------------------
template <int EPI>
__global__ __launch_bounds__(256) void gemm128(
    const __hip_bfloat16* __restrict__ A,
    const __hip_bfloat16* __restrict__ W,
    int K, int N,
    __hip_bfloat16* __restrict__ outb0,
    __hip_bfloat16* __restrict__ outb1,
    float* __restrict__ outf,
    const float* __restrict__ biasf)
{
  constexpr int BK = 32;
  constexpr int GY = 16;
  __shared__ short sA[128 * BK];
  __shared__ short sB[128 * BK];
  const int tid  = threadIdx.x;
  const int wid  = tid >> 6;
  const int lane = tid & 63;

  const int gx  = gridDim.x;
  const int id  = blockIdx.y * gx + blockIdx.x;
  const int seg = gx * GY;
  const int bx  = (id % seg) / GY;
  const int by  = (id / seg) * GY + (id % GY);

  const int m0 = by * 128;
  const int n0 = bx * 128;
  const int wm = (wid & 1) * 64;
  const int wn = (wid >> 1) * 64;

  floatx4 acc[4][4];
#pragma unroll
  for (int i = 0; i < 4; i++)
#pragma unroll
    for (int j = 0; j < 4; j++) acc[i][j] = (floatx4){0.f, 0.f, 0.f, 0.f};

  const short* Ag = (const short*)A + (size_t)(m0 + (tid >> 2)) * K + (tid & 3) * 8;
  const short* Bg = (const short*)W + (size_t)(n0 + (tid >> 2)) * K + (tid & 3) * 8;
  short* sAd = &sA[tid * 8];
  short* sBd = &sB[tid * 8];
  const size_t rstep = (size_t)64 * K;
  const int fr = lane & 15, fq = lane >> 4;

  for (int kb = 0; kb < K; kb += BK) {
    load16(Ag, sAd);
    load16(Ag + rstep, sAd + 2048);
    load16(Bg, sBd);
    load16(Bg + rstep, sBd + 2048);
    Ag += BK; Bg += BK;
    __syncthreads();

    short8 av[4], bv[4];
#pragma unroll
    for (int mt = 0; mt < 4; mt++) av[mt] = *(const short8*)&sA[(wm + mt * 16 + fr) * BK + fq * 8];
#pragma unroll
    for (int nt = 0; nt < 4; nt++) bv[nt] = *(const short8*)&sB[(wn + nt * 16 + fr) * BK + fq * 8];
#pragma unroll
    for (int mt = 0; mt < 4; mt++)
#pragma unroll
      for (int nt = 0; nt < 4; nt++)
        acc[mt][nt] = __builtin_amdgcn_mfma_f32_16x16x32_bf16(av[mt], bv[nt], acc[mt][nt], 0, 0, 0);
    __syncthreads();
  }

#pragma unroll
  for (int mt = 0; mt < 4; mt++) {
#pragma unroll
    for (int nt = 0; nt < 4; nt++) {
#pragma unroll
      for (int r = 0; r < 4; r++) {
        const int gm = m0 + wm + mt * 16 + fq * 4 + r;
        const int gn = n0 + wn + nt * 16 + fr;
        float v = acc[mt][nt][r];
        if constexpr (EPI == 0) {
          if (gn < 1024) outb0[(size_t)gm * 1024 + gn] = __float2bfloat16(v);
          else           outb1[(size_t)gm * 1024 + (gn - 1024)] = __float2bfloat16(v);
        } else if constexpr (EPI == 1) {
          v += biasf[gn];
          v = (v > 15.f) ? v : __logf(1.f + __expf(v));
          outb0[(size_t)gm * N + gn] = __float2bfloat16(v);
        } else {
          outf[(size_t)gm * N + gn] = v;
        }
      }
    }
  }
}

// ---------------------------------------------------------------------------
// 256x256 8-phase MFMA GEMM — VERIFIED round-2 version (passed, 76 µs,
// MfmaUtil 37%). Unchanged.
// ---------------------------------------------------------------------------
__device__ __forceinline__ void wait_lgkm0() {
  asm volatile("s_waitcnt lgkmcnt(0)");
  __builtin_amdgcn_sched_barrier(0);
}

template <int EPI>
__device__ __forceinline__ void cluster_mfma(int MQ, floatx4 (&acc)[8][4],
                                             const short8 (&av)[8][2],
                                             const short8 (&bv)[4][2])
{
  __builtin_amdgcn_s_setprio(1);
#pragma unroll
  for (int j = 0; j < 2; j++)
#pragma unroll
    for (int nf = 0; nf < 4; nf++)
#pragma unroll
      for (int ks = 0; ks < 2; ks++)
        acc[2 * MQ + j][nf] = __builtin_amdgcn_mfma_f32_16x16x32_bf16(
            av[2 * MQ + j][ks], bv[nf][ks], acc[2 * MQ + j][nf], 0, 0, 0);
  __builtin_amdgcn_s_setprio(0);
}

template <int EPI>
__global__ __launch_bounds__(512, 2) void gemm256(
    const __hip_bfloat16* __restrict__ A,
    const __hip_bfloat16* __restrict__ W,
    int K, int N,
    __hip_bfloat16* __restrict__ outb0,
    __hip_bfloat16* __restrict__ outb1,
    float* __restrict__ outf)
{
  __shared__ alignas(16) char lds[131072];
  const int tid  = threadIdx.x;
  const int wid  = tid >> 6;
  const int lane = tid & 63;
  const int wm = wid >> 2;      // 0..1
  const int wn = wid & 3;       // 0..3
  const int fr = lane & 15, fq = lane >> 4;

  // Bijective XCD swizzle (nwg % 8 == 0 for all launches here).
  const int gx   = gridDim.x;
  const int nwg  = gx * gridDim.y;
  const int orig = blockIdx.y * gx + blockIdx.x;
  const int swz  = (orig & 7) * (nwg >> 3) + (orig >> 3);
  const int bx   = swz % gx;
  const int by   = swz / gx;
  const int m0 = by * 256;
  const int n0 = bx * 256;
  const size_t K2 = (size_t)K * 2;   // row bytes

  int rowo[2], colo[2];
#pragma unroll
  for (int i = 0; i < 2; i++) {
    const int p = i * 8192 + tid * 16;
    const int s = p >> 10;           // subtile 0..15 (rb*2+cb)
    const int r = (p >> 6) & 15;     // row within subtile
    rowo[i] = (s >> 1) * 16 + r;                                  // 0..127
    colo[i] = (s & 1) * 64 + ((p & 63) ^ (((r >> 3) & 1) << 5));  // byte 0..127
  }
  const char* Ab = (const char*)A + (size_t)m0 * K2;
  const char* Bb = (const char*)W + (size_t)n0 * K2;
  char* lbase = (char*)lds;

#define STAGE_A(c, h, kt) do {                                                          \
    load16(Ab + (size_t)((h) * 128 + rowo[0]) * K2 + (size_t)(kt) * 128 + colo[0],      \
           lbase + (c) * 32768 + (h) * 16384 + tid * 16);                               \
    load16(Ab + (size_t)((h) * 128 + rowo[1]) * K2 + (size_t)(kt) * 128 + colo[1],      \
           lbase + (c) * 32768 + (h) * 16384 + 8192 + tid * 16);                        \
  } while (0)
#define STAGE_B(c, h, kt) do {                                                          \
    load16(Bb + (size_t)((h) * 128 + rowo[0]) * K2 + (size_t)(kt) * 128 + colo[0],      \
           lbase + 65536 + (c) * 32768 + (h) * 16384 + tid * 16);                       \
    load16(Bb + (size_t)((h) * 128 + rowo[1]) * K2 + (size_t)(kt) * 128 + colo[1],      \
           lbase + 65536 + (c) * 32768 + (h) * 16384 + 8192 + tid * 16);                \
  } while (0)

  const int foff = (fr * 64 + fq * 16) ^ (((fr >> 3) & 1) << 5);

  floatx4 acc[8][4];
#pragma unroll
  for (int i = 0; i < 8; i++)
#pragma unroll
    for (int j = 0; j < 4; j++) acc[i][j] = (floatx4){0.f, 0.f, 0.f, 0.f};

  // Prologue: K0 all 4 halves, then K1 {B0,B1,A0}. vmcnt(6) => K0 landed.
  STAGE_A(0, 0, 0); STAGE_A(0, 1, 0); STAGE_B(0, 0, 0); STAGE_B(0, 1, 0);
  STAGE_B(1, 0, 1); STAGE_B(1, 1, 1); STAGE_A(1, 0, 1);
  asm volatile("s_waitcnt vmcnt(6)");
  __builtin_amdgcn_sched_barrier(0);
  __builtin_amdgcn_s_barrier();

  const int NT = K >> 6;
  short8 av[8][2], bv[4][2];
#pragma unroll 2
  for (int t = 0; t < NT; ++t) {
    const int cur = t & 1, nxt = cur ^ 1;
    const char* la = lbase + cur * 32768 + wm * 16384 + foff;
    const char* lb = lbase + 65536 + cur * 32768 + (wn >> 1) * 16384 + (wn & 1) * 8192 + foff;

    // ---------------- phase 1: all B frags + av[0,1]; stage A1(t+1)->nxt
#pragma unroll
    for (int nf = 0; nf < 4; nf++)
#pragma unroll
      for (int ks = 0; ks < 2; ks++)
        bv[nf][ks] = *(const short8*)(lb + (nf * 2 + ks) * 1024);
#pragma unroll
    for (int mf = 0; mf < 2; mf++)
#pragma unroll
      for (int ks = 0; ks < 2; ks++)
        av[mf][ks] = *(const short8*)(la + (mf * 2 + ks) * 1024);
    if (t + 1 < NT) STAGE_A(nxt, 1, t + 1);
    __builtin_amdgcn_s_barrier();
    wait_lgkm0();
    cluster_mfma<EPI>(0, acc, av, bv);
    __builtin_amdgcn_s_barrier();

    // ---------------- phase 2: av[2,3]; stage B0(t+2)->cur (B reads done ph1)
#pragma unroll
    for (int mf = 2; mf < 4; mf++)
#pragma unroll
      for (int ks = 0; ks < 2; ks++)
        av[mf][ks] = *(const short8*)(la + (mf * 2 + ks) * 1024);
    if (t + 2 < NT) STAGE_B(cur, 0, t + 2);
    __builtin_amdgcn_s_barrier();
    wait_lgkm0();
    cluster_mfma<EPI>(1, acc, av, bv);
    __builtin_amdgcn_s_barrier();

    // ---------------- phase 3: av[4..7]; stage B1(t+2)->cur
#pragma unroll
    for (int mf = 4; mf < 8; mf++)
#pragma unroll
      for (int ks = 0; ks < 2; ks++)
        av[mf][ks] = *(const short8*)(la + (mf * 2 + ks) * 1024);
    if (t + 2 < NT) STAGE_B(cur, 1, t + 2);
    __builtin_amdgcn_s_barrier();
    wait_lgkm0();
    cluster_mfma<EPI>(2, acc, av, bv);
    __builtin_amdgcn_s_barrier();

    // ---------------- phase 4: no reads; stage A0(t+2)->cur (A reads done ph3)
    if (t + 2 < NT) STAGE_A(cur, 0, t + 2);
    __builtin_amdgcn_s_barrier();
    cluster_mfma<EPI>(3, acc, av, bv);
    // counted vmcnt once per K-tile: 3 newest half-tiles (6 loads) in flight.
    if (t < NT - 2) {
      asm volatile("s_waitcnt vmcnt(6)");
      __builtin_amdgcn_sched_barrier(0);
      __builtin_amdgcn_s_barrier();
    } else if (t == NT - 2) {
      asm volatile("s_waitcnt vmcnt(0)");
      __builtin_amdgcn_sched_barrier(0);
      __builtin_amdgcn_s_barrier();
    } // t == NT-1: fall through to epilogue
  }
#undef STAGE_A
#undef STAGE_B

#pragma unroll
  for (int mf = 0; mf < 8; mf++) {
#pragma unroll
    for (int nf = 0; nf < 4; nf++) {
#pragma unroll
      for (int r = 0; r < 4; r++) {
        const int gm = m0 + wm * 128 + mf * 16 + fq * 4 + r;
        const int gn = n0 + wn * 64 + nf * 16 + fr;
        const float v = acc[mf][nf][r];
        if constexpr (EPI == 0) {
          if (gn < 1024) outb0[(size_t)gm * 1024 + gn] = __float2bfloat16(v);
          else           outb1[(size_t)gm * 1024 + (gn - 1024)] = __float2bfloat16(v);
        } else {
          outf[(size_t)gm * N + gn] = v;
        }
      }
    }
  }
}

// ---------------------------------------------------------------------------
// x_proj GEMM, split-K x4: partial[kc][M,66] = u[M, kc-chunk] * xpw[66, kc-chunk]^T
// ---------------------------------------------------------------------------
__global__ __launch_bounds__(256) void gemm_xproj(
    const __hip_bfloat16* __restrict__ A,
    const __hip_bfloat16* __restrict__ W,
    float* __restrict__ part)
{
  constexpr int K = 1024, BK = 32, KC = K / XPJ_KS; // 256
  __shared__ short sA[128 * BK];
  __shared__ short sB[80 * BK];
  const int tid = threadIdx.x;
  const int wid = tid >> 6, lane = tid & 63;
  const int kc = blockIdx.x;
  const int m0 = blockIdx.y * 128;

  floatx4 acc[2][5];
#pragma unroll
  for (int i = 0; i < 2; i++)
#pragma unroll
    for (int j = 0; j < 5; j++) acc[i][j] = (floatx4){0.f, 0.f, 0.f, 0.f};

  const short* Ag = (const short*)A + (size_t)(m0 + (tid >> 2)) * K + kc * KC + (tid & 3) * 8;
  const int brow2 = 64 + (tid >> 2);
  const int brow2c = brow2 > 65 ? 65 : brow2;
  const short* Bg  = (const short*)W + (size_t)(tid >> 2) * K + kc * KC + (tid & 3) * 8;
  const short* Bg2 = (const short*)W + (size_t)brow2c * K + kc * KC + (tid & 3) * 8;
  const size_t rstep = (size_t)64 * K;
  const int fr = lane & 15, fq = lane >> 4;

  for (int kb = 0; kb < KC; kb += BK) {
    load16(Ag, &sA[tid * 8]);
    load16(Ag + rstep, &sA[2048 + tid * 8]);
    load16(Bg, &sB[tid * 8]);
    if (tid < 64) load16(Bg2, &sB[2048 + tid * 8]);
    Ag += BK; Bg += BK; Bg2 += BK;
    __syncthreads();

    short8 av[2], bv[5];
#pragma unroll
    for (int mt = 0; mt < 2; mt++) av[mt] = *(const short8*)&sA[(wid * 32 + mt * 16 + fr) * BK + fq * 8];
#pragma unroll
    for (int nt = 0; nt < 5; nt++) bv[nt] = *(const short8*)&sB[(nt * 16 + fr) * BK + fq * 8];
#pragma unroll
    for (int mt = 0; mt < 2; mt++)
#pragma unroll
      for (int nt = 0; nt < 5; nt++)
        acc[mt][nt] = __builtin_amdgcn_mfma_f32_16x16x32_bf16(av[mt], bv[nt], acc[mt][nt], 0, 0, 0);
    __syncthreads();
  }

  float* pp = part + (size_t)kc * Mrows * 66;
#pragma unroll
  for (int mt = 0; mt < 2; mt++) {
#pragma unroll
    for (int nt = 0; nt < 5; nt++) {
#pragma unroll
      for (int r = 0; r < 4; r++) {
        const int gm = m0 + wid * 32 + mt * 16 + fq * 4 + r;
        const int gn = nt * 16 + fr;
        if (gn < 66) pp[(size_t)gm * 66 + gn] = acc[mt][nt][r];
      }
    }
  }
}

__global__ __launch_bounds__(256) void xproj_reduce(
    const float* __restrict__ part,
    __hip_bfloat16* __restrict__ dts,
    float* __restrict__ Bs, float* __restrict__ Cs)
{
  const int i = blockIdx.x * 256 + threadIdx.x;
  if (i >= Mrows * 66) return;
  const int gm = i / 66, gn = i - gm * 66;
  float s = part[i] + part[i + (size_t)Mrows * 66]
          + part[i + (size_t)2 * Mrows * 66] + part[i + (size_t)3 * Mrows * 66];
  if (gn < 64)       dts[(size_t)gm * 64 + gn] = __float2bfloat16(s);
  else if (gn == 64) Bs[gm] = s;
  else               Cs[gm] = s;
}

// ---------------------------------------------------------------------------
// Causal depthwise conv (k=2) + bias + SiLU.  Vectorized: 8 d-elems/thread
// (16B bf16 loads/stores — G13; was 2B/lane scalar).
// ---------------------------------------------------------------------------
__global__ __launch_bounds__(256) void conv_silu(
    const __hip_bfloat16* __restrict__ xc, const float* __restrict__ cw,
    const float* __restrict__ cb, __hip_bfloat16* __restrict__ u)
{
  const size_t i8 = ((size_t)blockIdx.x * 256 + threadIdx.x) * 8;
  const int d8 = (int)(i8 & (Di - 1));
  const int l  = (int)((i8 >> 10) & (Lz - 1));
  const short8 cur = *(const short8*)((const short*)xc + i8);
  short8 prv;
  if (l > 0) prv = *(const short8*)((const short*)xc + i8 - Di);
  else       prv = (short8){0, 0, 0, 0, 0, 0, 0, 0};
  const float4* cw4 = (const float4*)(cw + 2 * d8);
  const float4 wA = cw4[0], wB = cw4[1], wC = cw4[2], wD = cw4[3];
  const float w0a[8] = {wA.x, wA.z, wB.x, wB.z, wC.x, wC.z, wD.x, wD.z};
  const float w1a[8] = {wA.y, wA.w, wB.y, wB.w, wC.y, wC.w, wD.y, wD.w};
  const float4* cb4 = (const float4*)(cb + d8);
  const float4 b0 = cb4[0], b1 = cb4[1];
  const float ba[8] = {b0.x, b0.y, b0.z, b0.w, b1.x, b1.y, b1.z, b1.w};
  short8 out;
#pragma unroll
  for (int k = 0; k < 8; k++) {
    const float pc = __uint_as_float(((uint32_t)(uint16_t)prv[k]) << 16);
    const float cc = __uint_as_float(((uint32_t)(uint16_t)cur[k]) << 16);
    const float v = pc * w0a[k] + cc * w1a[k] + ba[k];
    const float s = v / (1.f + __expf(-v));
    out[k] = f2bfs(s);
  }
  *(short8*)((short*)u + i8) = out;
}

// ---------------------------------------------------------------------------
// Chunked scan, D_STATE=1:  h[l] = exp(delta*A)*h[l-1] + delta*Bs*u
// CH=32 (1024 wg for p1/p3 = 4 waves/SIMD), 2 d's/thread (4B loads).
// ---------------------------------------------------------------------------
__global__ __launch_bounds__(256) void scan_p1(
    const __hip_bfloat16* __restrict__ delta, const __hip_bfloat16* __restrict__ u,
    const float* __restrict__ Bsv, const float* __restrict__ A_logs,
    float* __restrict__ carryP, float* __restrict__ carryS)
{
  const int dp = blockIdx.x * 256 + threadIdx.x;   // d-pair 0..511
  const int d  = dp * 2;
  const int c = blockIdx.y, b = blockIdx.z;
  const float2 Al = *(const float2*)(A_logs + d);
  const float Ac0 = -__expf(Al.x), Ac1 = -__expf(Al.y);
  const size_t base = ((size_t)(b * Lz + c * CH)) * Di + d;
  const float* Bp = Bsv + (size_t)b * Lz + c * CH;
  float P0 = 1.f, h0 = 0.f, P1 = 1.f, h1 = 0.f;
#pragma unroll 8
  for (int j = 0; j < CH; j++) {
    const uint32_t dv = *(const uint32_t*)((const uint16_t*)delta + base + (size_t)j * Di);
    const uint32_t uv = *(const uint32_t*)((const uint16_t*)u + base + (size_t)j * Di);
    const float dl0 = __uint_as_float(dv << 16);
    const float dl1 = __uint_as_float(dv & 0xffff0000u);
    const float uu0 = __uint_as_float(uv << 16);
    const float uu1 = __uint_as_float(uv & 0xffff0000u);
    const float bj  = Bp[j];
    const float a0 = __expf(dl0 * Ac0), a1 = __expf(dl1 * Ac1);
    h0 = a0 * h0 + dl0 * bj * uu0;
    h1 = a1 * h1 + dl1 * bj * uu1;
    P0 *= a0; P1 *= a1;
  }
  const size_t ci = ((size_t)(b * NCH + c)) * Di + d;
  *(float2*)(carryP + ci) = make_float2(P0, P1);
  *(float2*)(carryS + ci) = make_float2(h0, h1);
}

__global__ __launch_bounds__(64) void scan_p2(
    const float* __restrict__ carryP, const float* __restrict__ carryS,
    float* __restrict__ hin)
{
  const int t = blockIdx.x * 64 + threadIdx.x;   // 0..4095
  const int b = t >> 10, d = t & (Di - 1);
  float h = 0.f;
  for (int c = 0; c < NCH; c++) {
    const size_t ci = ((size_t)(b * NCH + c)) * Di + d;
    hin[ci] = h;
    h = carryP[ci] * h + carryS[ci];
  }
}

__global__ __launch_bounds__(256) void scan_p3(
    const __hip_bfloat16* __restrict__ delta, __hip_bfloat16* __restrict__ uy,
    const float* __restrict__ Bsv, const float* __restrict__ Csv,
    const float* __restrict__ A_logs, const float* __restrict__ Ds,
    const float* __restrict__ hin)
{
  const int dp = blockIdx.x * 256 + threadIdx.x;
  const int d  = dp * 2;
  const int c = blockIdx.y, b = blockIdx.z;
  const float2 Al = *(const float2*)(A_logs + d);
  const float Ac0 = -__expf(Al.x), Ac1 = -__expf(Al.y);
  const float2 Dd = *(const float2*)(Ds + d);
  const size_t base = ((size_t)(b * Lz + c * CH)) * Di + d;
  const float* Bp = Bsv + (size_t)b * Lz + c * CH;
  const float* Cp = Csv + (size_t)b * Lz + c * CH;
  const size_t ci = ((size_t)(b * NCH + c)) * Di + d;
  const float2 hh = *(const float2*)(hin + ci);
  float h0 = hh.x, h1 = hh.y;
#pragma unroll 8
  for (int j = 0; j < CH; j++) {
    const size_t ix = base + (size_t)j * Di;
    const uint32_t dv = *(const uint32_t*)((const uint16_t*)delta + ix);
    const uint32_t uv = *(const uint32_t*)((const uint16_t*)uy + ix);
    const float dl0 = __uint_as_float(dv << 16);
    const float dl1 = __uint_as_float(dv & 0xffff0000u);
    const float uu0 = __uint_as_float(uv << 16);
    const float uu1 = __uint_as_float(uv & 0xffff0000u);
    const float bj = Bp[j], cj = Cp[j];
    const float a0 = __expf(dl0 * Ac0), a1 = __expf(dl1 * Ac1);
    h0 = a0 * h0 + dl0 * bj * uu0;
    h1 = a1 * h1 + dl1 * bj * uu1;
    const float y0 = h0 * cj + uu0 * Dd.x;
    const float y1 = h1 * cj + uu1 * Dd.y;
    const uint32_t o = (uint32_t)(uint16_t)f2bfs(y0) | ((uint32_t)(uint16_t)f2bfs(y1) << 16);
    *(uint32_t*)((uint16_t*)uy + ix) = o;
  }
}

// ---------------------------------------------------------------------------
// LayerNorm over D=1024 + SiLU(z) gate -> bf16.  z-load and store vectorized.
// ---------------------------------------------------------------------------
__global__ __launch_bounds__(256) void ln_gate(
    const __hip_bfloat16* __restrict__ y, const __hip_bfloat16* __restrict__ z,
    const float* __restrict__ lnw, const float* __restrict__ lnb,
    __hip_bfloat16* __restrict__ yg)
{
  const int row = blockIdx.x;
  const int tid = threadIdx.x;
  const int wid = tid >> 6, lane = tid & 63;
  const short4v yv = *(const short4v*)((const short*)y + (size_t)row * Di + tid * 4);
  const short4v zv4 = *(const short4v*)((const short*)z + (size_t)row * Di + tid * 4);
  float v[4];
#pragma unroll
  for (int i = 0; i < 4; i++)
    v[i] = __uint_as_float(((uint32_t)(uint16_t)yv[i]) << 16);
  float s1 = v[0] + v[1] + v[2] + v[3];
  float s2 = v[0] * v[0] + v[1] * v[1] + v[2] * v[2] + v[3] * v[3];
#pragma unroll
  for (int o = 32; o > 0; o >>= 1) {
    s1 += __shfl_down(s1, o, 64);
    s2 += __shfl_down(s2, o, 64);
  }
  __shared__ float r1[4], r2[4];
  if (lane == 0) { r1[wid] = s1; r2[wid] = s2; }
  __syncthreads();
  const float t1 = r1[0] + r1[1] + r1[2] + r1[3];
  const float t2 = r2[0] + r2[1] + r2[2] + r2[3];
  const float mu = t1 * (1.f / Di);
  const float var = t2 * (1.f / Di) - mu * mu;
  const float rstd = rsqrtf(var + 1e-5f);

  const float4 wv = ((const float4*)lnw)[tid];
  const float4 bv = ((const float4*)lnb)[tid];
  const float wa[4] = {wv.x, wv.y, wv.z, wv.w};
  const float ba[4] = {bv.x, bv.y, bv.z, bv.w};
  short4v og;
#pragma unroll
  for (int i = 0; i < 4; i++) {
    const float zz = __uint_as_float(((uint32_t)(uint16_t)zv4[i]) << 16);
    const float g = zz / (1.f + __expf(-zz));
    og[i] = f2bfs(((v[i] - mu) * rstd * wa[i] + ba[i]) * g);
  }
  *(short4v*)((short*)yg + (size_t)row * Di + tid * 4) = og;
}

// ---------------------------------------------------------------------------
// Diagnostic: fill d_out (f32) with ws_size expressed in KiB (read via absmax).
// ---------------------------------------------------------------------------
__global__ __launch_bounds__(256) void fill_diag(float* __restrict__ out, int n, float val)
{
  const int i = blockIdx.x * 256 + threadIdx.x;
  if (i < n) out[i] = val;
}

// ---------------------------------------------------------------------------
extern "C" void kernel_launch(void* const* d_in, const int* in_sizes, int n_in,
                              void* d_out, int out_size, void* d_ws, size_t ws_size,
                              hipStream_t stream)
{
  const float* x      = (const float*)d_in[0];
  const float* w_in   = (const float*)d_in[1];
  const float* conv_w = (const float*)d_in[2];
  const float* conv_b = (const float*)d_in[3];
  const float* xpw    = (const float*)d_in[4];
  const float* dtw    = (const float*)d_in[5];
  const float* dtb    = (const float*)d_in[6];
  const float* A_logs = (const float*)d_in[7];
  const float* Ds     = (const float*)d_in[8];
  const float* lnw    = (const float*)d_in[9];
  const float* lnb    = (const float*)d_in[10];
  const float* w_out  = (const float*)d_in[11];
  float* outF = (float*)d_out;   // 16.7M f32 = 64 MiB

  const size_t BF16BIG  = (size_t)Mrows * Di * sizeof(__hip_bfloat16); // 32 MiB
  const size_t NEED_RUN = 69603328;  // exact ws usage below (unchanged)

  if (ws_size < NEED_RUN) {
    fill_diag<<<(out_size + 255) / 256, 256, 0, stream>>>(
        outF, out_size, (float)(ws_size >> 10));
    return;
  }

  uint8_t* ws = (uint8_t*)d_ws;
  size_t off = 0;
  auto alloc = [&](size_t bytes) { void* p = ws + off; off += (bytes + 255) & ~(size_t)255; return p; };

  // ws layout (66.4 MiB total):
  __hip_bfloat16* slotA    = (__hip_bfloat16*)alloc(BF16BIG);   // xc -> delta -> yg
  __hip_bfloat16* slotC    = (__hip_bfloat16*)alloc(BF16BIG);   // xbf -> u -> y (in-place)
  __hip_bfloat16* w_out_bf = (__hip_bfloat16*)alloc((size_t)Dm * Di * 2);
  __hip_bfloat16* xpw_bf   = (__hip_bfloat16*)alloc((size_t)66 * Di * 2);
  __hip_bfloat16* dtw_bf   = (__hip_bfloat16*)alloc((size_t)Di * 64 * 2);
  float* Bsv = (float*)alloc((size_t)Mrows * sizeof(float));
  float* Csv = (float*)alloc((size_t)Mrows * sizeof(float));

  // d_out (64 MiB f32) doubles as scratch for regions dead before stage 9:
  //  [0,32M):  z (alive until stage 8)
  //  [32,36M): w_in_bf (dead after stage 1)
  //  [36,38M): dts (bf16, dead after stage 4)
  //  [38,40M): carryP (2MB, written stage 5)
  //  [40,42M): carryS (2MB; overlaps xpj_part head — dead after stage 3)
  //  [42,44M): hin    (2MB; ditto)
  //  [40M,57.3M): xpj_part (f32, dead after stage 3)
  __hip_bfloat16* zbuf    = (__hip_bfloat16*)d_out;
  __hip_bfloat16* w_in_bf = (__hip_bfloat16*)((uint8_t*)d_out + 33554432);
  __hip_bfloat16* dts     = (__hip_bfloat16*)((uint8_t*)d_out + 37748736);
  float* carryP = (float*)((uint8_t*)d_out + 39845888);
  float* carryS = (float*)((uint8_t*)d_out + 41943040);
  float* hin    = (float*)((uint8_t*)d_out + 44040192);
  float* xpj_part = (float*)((uint8_t*)d_out + 41943040);  // overlaps carryS/hin (dead by scan)

  __hip_bfloat16* xbf   = slotC;   // dead after stage 1 (overwritten by u)
  __hip_bfloat16* xcbuf = slotA;
  __hip_bfloat16* ubuf  = slotC;
  __hip_bfloat16* delta = slotA;   // overwrites xc (dead after conv)
  __hip_bfloat16* yg    = slotA;   // overwrites delta (dead after scan_p3)

  // 0. convert f32 inputs -> bf16 working copies (one fused launch)
  cvt_all<<<(5014016 + 255) / 256, 256, 0, stream>>>(
      x, w_in, w_out, xpw, dtw, xbf, w_in_bf, w_out_bf, xpw_bf, dtw_bf);

  // 1. xz = x @ w_in^T -> xc (slotA), z (d_out[0,32M))  [verified 256^2 8-phase]
  gemm256<0><<<dim3(2 * Di / 256, Mrows / 256), 512, 0, stream>>>(
      xbf, w_in_bf, Dm, 2 * Di, xcbuf, zbuf, nullptr);
  // 2. conv + silu -> u (slotC; xbf dead)
  conv_silu<<<(Mrows * Di / 8) / 256, 256, 0, stream>>>(xcbuf, conv_w, conv_b, ubuf);
  // 3. x_proj split-K -> partials -> reduce to dts, Bs, Cs
  gemm_xproj<<<dim3(XPJ_KS, Mrows / 128), 256, 0, stream>>>(ubuf, xpw_bf, xpj_part);
  xproj_reduce<<<(Mrows * 66 + 255) / 256, 256, 0, stream>>>(xpj_part, dts, Bsv, Csv);
  // 4. delta = softplus(dts @ dtw^T + bias) -> slotA (xc dead)  [K=64, mem-bound]
  gemm128<1><<<dim3(Di / 128, Mrows / 128), 256, 0, stream>>>(
      dts, dtw_bf, 64, Di, delta, nullptr, nullptr, dtb);
  // 5-7. chunked scan (CH=32); y written in-place over u
  scan_p1<<<dim3(Di / 512, NCH, Bz), 256, 0, stream>>>(delta, ubuf, Bsv, A_logs, carryP, carryS);
  scan_p2<<<(Bz * Di) / 64, 64, 0, stream>>>(carryP, carryS, hin);
  scan_p3<<<dim3(Di / 512, NCH, Bz), 256, 0, stream>>>(delta, ubuf, Bsv, Csv, A_logs, Ds, hin);
  // 8. layernorm + silu(z) gate -> yg (slotA; delta dead)
  ln_gate<<<Mrows, 256, 0, stream>>>(ubuf, zbuf, lnw, lnb, yg);
  // 9. out = yg @ w_out^T -> d_out f32 (overwrites all d_out scratch — dead)
  gemm256<1><<<dim3(Dm / 256, Mrows / 256), 512, 0, stream>>>(
      yg, w_out_bf, Di, Dm, nullptr, nullptr, outF);
}

// Round 7
// 351.895 us; speedup vs baseline: 1.1669x; 1.0047x over previous
//
#include <hip/hip_runtime.h>
#include <hip/hip_bf16.h>
#include <cstdint>
#include <cstddef>

typedef short short8 __attribute__((ext_vector_type(8)));
typedef short short4v __attribute__((ext_vector_type(4)));
typedef float floatx4 __attribute__((ext_vector_type(4)));

constexpr int Bz = 4;
constexpr int Lz = 4096;
constexpr int Dm = 1024;       // d_model
constexpr int Di = 1024;       // d_inner
constexpr int Mrows = Bz * Lz; // 16384
constexpr int CH  = 32;        // scan chunk length
constexpr int NCH = Lz / CH;   // 128
constexpr int XPJ_KS = 4;      // x_proj split-K factor

__device__ __forceinline__ void load16(const void* g, void* l) {
  __builtin_amdgcn_global_load_lds((__attribute__((address_space(1))) void*)g,
                                   (__attribute__((address_space(3))) void*)l,
                                   16, 0, 0);
}

__device__ __forceinline__ float bf2f(const __hip_bfloat16 v) { return __bfloat162float(v); }
__device__ __forceinline__ short f2bfs(float v) {
  __hip_bfloat16 h = __float2bfloat16(v);
  return *(short*)&h;
}

// ---------------------------------------------------------------------------
// All f32->bf16 conversions (x + 4 weight matrices) in ONE launch.
// Ranges in units of 4 floats.
// ---------------------------------------------------------------------------
__global__ __launch_bounds__(256) void cvt_all(
    const float* __restrict__ x, const float* __restrict__ w_in,
    const float* __restrict__ w_out, const float* __restrict__ xpw,
    const float* __restrict__ dtw,
    __hip_bfloat16* __restrict__ xbf, __hip_bfloat16* __restrict__ w_in_bf,
    __hip_bfloat16* __restrict__ w_out_bf, __hip_bfloat16* __restrict__ xpw_bf,
    __hip_bfloat16* __restrict__ dtw_bf)
{
  const int i = blockIdx.x * 256 + threadIdx.x;
  const float* src; __hip_bfloat16* dst; int j;
  if (i < 4194304)      { src = x;     dst = xbf;      j = i; }            // 16M elems
  else if (i < 4718592) { src = w_in;  dst = w_in_bf;  j = i - 4194304; }  // 2M
  else if (i < 4980736) { src = w_out; dst = w_out_bf; j = i - 4718592; }  // 1M
  else if (i < 4997632) { src = xpw;   dst = xpw_bf;   j = i - 4980736; }  // 66K
  else if (i < 5014016) { src = dtw;   dst = dtw_bf;   j = i - 4997632; }  // 64K
  else return;
  const float4 v = ((const float4*)src)[j];
  short4v s;
  s[0] = f2bfs(v.x); s[1] = f2bfs(v.y); s[2] = f2bfs(v.z); s[3] = f2bfs(v.w);
  ((short4v*)dst)[j] = s;
}

// ---------------------------------------------------------------------------
// 128x128 MFMA GEMM (m97-class structure). Retained ONLY for the K=64
// delta GEMM (EPI 1), which is memory-bound.
// ---------------------------------------------------------------------------
template <int EPI>
__global__ __launch_bounds__(256) void gemm128(
    const __hip_bfloat16* __restrict__ A,
    const __hip_bfloat16* __restrict__ W,
    int K, int N,
    __hip_bfloat16* __restrict__ outb0,
    __hip_bfloat16* __restrict__ outb1,
    float* __restrict__ outf,
    const float* __restrict__ biasf)
{
  constexpr int BK = 32;
  constexpr int GY = 16;
  __shared__ short sA[128 * BK];
  __shared__ short sB[128 * BK];
  const int tid  = threadIdx.x;
  const int wid  = tid >> 6;
  const int lane = tid & 63;

  const int gx  = gridDim.x;
  const int id  = blockIdx.y * gx + blockIdx.x;
  const int seg = gx * GY;
  const int bx  = (id % seg) / GY;
  const int by  = (id / seg) * GY + (id % GY);

  const int m0 = by * 128;
  const int n0 = bx * 128;
  const int wm = (wid & 1) * 64;
  const int wn = (wid >> 1) * 64;

  floatx4 acc[4][4];
#pragma unroll
  for (int i = 0; i < 4; i++)
#pragma unroll
    for (int j = 0; j < 4; j++) acc[i][j] = (floatx4){0.f, 0.f, 0.f, 0.f};

  const short* Ag = (const short*)A + (size_t)(m0 + (tid >> 2)) * K + (tid & 3) * 8;
  const short* Bg = (const short*)W + (size_t)(n0 + (tid >> 2)) * K + (tid & 3) * 8;
  short* sAd = &sA[tid * 8];
  short* sBd = &sB[tid * 8];
  const size_t rstep = (size_t)64 * K;
  const int fr = lane & 15, fq = lane >> 4;

  for (int kb = 0; kb < K; kb += BK) {
    load16(Ag, sAd);
    load16(Ag + rstep, sAd + 2048);
    load16(Bg, sBd);
    load16(Bg + rstep, sBd + 2048);
    Ag += BK; Bg += BK;
    __syncthreads();

    short8 av[4], bv[4];
#pragma unroll
    for (int mt = 0; mt < 4; mt++) av[mt] = *(const short8*)&sA[(wm + mt * 16 + fr) * BK + fq * 8];
#pragma unroll
    for (int nt = 0; nt < 4; nt++) bv[nt] = *(const short8*)&sB[(wn + nt * 16 + fr) * BK + fq * 8];
#pragma unroll
    for (int mt = 0; mt < 4; mt++)
#pragma unroll
      for (int nt = 0; nt < 4; nt++)
        acc[mt][nt] = __builtin_amdgcn_mfma_f32_16x16x32_bf16(av[mt], bv[nt], acc[mt][nt], 0, 0, 0);
    __syncthreads();
  }

#pragma unroll
  for (int mt = 0; mt < 4; mt++) {
#pragma unroll
    for (int nt = 0; nt < 4; nt++) {
#pragma unroll
      for (int r = 0; r < 4; r++) {
        const int gm = m0 + wm + mt * 16 + fq * 4 + r;
        const int gn = n0 + wn + nt * 16 + fr;
        float v = acc[mt][nt][r];
        if constexpr (EPI == 0) {
          if (gn < 1024) outb0[(size_t)gm * 1024 + gn] = __float2bfloat16(v);
          else           outb1[(size_t)gm * 1024 + (gn - 1024)] = __float2bfloat16(v);
        } else if constexpr (EPI == 1) {
          v += biasf[gn];
          v = (v > 15.f) ? v : __logf(1.f + __expf(v));
          outb0[(size_t)gm * N + gn] = __float2bfloat16(v);
        } else {
          outf[(size_t)gm * N + gn] = v;
        }
      }
    }
  }
}

// ---------------------------------------------------------------------------
// 256x256 4-phase MFMA GEMM — round-2 verified structure with the REDUNDANT
// begin-barrier of each phase removed (8 -> 4 barriers per K-tile).
//
// Hazard ledger (identical invariant to the verified round-2 kernel):
//  * WAR: every phase's ds_reads are drained by that wave's lgkmcnt(0)
//    BEFORE the phase-end barrier; any stage into those regions is issued
//    only AFTER that barrier. (B-h0/h1 reads drain in ph1 -> staged ph2/ph3;
//    A-h0 reads drain by ph3 -> staged ph4; A-h1 of buf nxt last read one
//    full iteration ago.)
//  * RAW: each wave's vmcnt(6) before the iter-end barrier collectively
//    certifies tile t+1 fully resident (prologue 8-of-14 drain; steady-state
//    drains {B0,B1,A0}(t+1)+A1(t+1); tail vmcnt(0) at t==NT-2).
//  * MFMA order per accumulator unchanged -> bit-identical output.
// The removed begin-barriers appear in no clause of the proof.
// ---------------------------------------------------------------------------
__device__ __forceinline__ void wait_lgkm0() {
  asm volatile("s_waitcnt lgkmcnt(0)");
  __builtin_amdgcn_sched_barrier(0);
}

template <int EPI>
__device__ __forceinline__ void cluster_mfma(int MQ, floatx4 (&acc)[8][4],
                                             const short8 (&av)[8][2],
                                             const short8 (&bv)[4][2])
{
  __builtin_amdgcn_s_setprio(1);
#pragma unroll
  for (int j = 0; j < 2; j++)
#pragma unroll
    for (int nf = 0; nf < 4; nf++)
#pragma unroll
      for (int ks = 0; ks < 2; ks++)
        acc[2 * MQ + j][nf] = __builtin_amdgcn_mfma_f32_16x16x32_bf16(
            av[2 * MQ + j][ks], bv[nf][ks], acc[2 * MQ + j][nf], 0, 0, 0);
  __builtin_amdgcn_s_setprio(0);
}

template <int EPI>
__global__ __launch_bounds__(512, 2) void gemm256(
    const __hip_bfloat16* __restrict__ A,
    const __hip_bfloat16* __restrict__ W,
    int K, int N,
    __hip_bfloat16* __restrict__ outb0,
    __hip_bfloat16* __restrict__ outb1,
    float* __restrict__ outf)
{
  __shared__ alignas(16) char lds[131072];
  const int tid  = threadIdx.x;
  const int wid  = tid >> 6;
  const int lane = tid & 63;
  const int wm = wid >> 2;      // 0..1
  const int wn = wid & 3;       // 0..3
  const int fr = lane & 15, fq = lane >> 4;

  // Bijective XCD swizzle (nwg % 8 == 0 for all launches here).
  const int gx   = gridDim.x;
  const int nwg  = gx * gridDim.y;
  const int orig = blockIdx.y * gx + blockIdx.x;
  const int swz  = (orig & 7) * (nwg >> 3) + (orig >> 3);
  const int bx   = swz % gx;
  const int by   = swz / gx;
  const int m0 = by * 256;
  const int n0 = bx * 256;
  const size_t K2 = (size_t)K * 2;   // row bytes

  int rowo[2], colo[2];
#pragma unroll
  for (int i = 0; i < 2; i++) {
    const int p = i * 8192 + tid * 16;
    const int s = p >> 10;           // subtile 0..15 (rb*2+cb)
    const int r = (p >> 6) & 15;     // row within subtile
    rowo[i] = (s >> 1) * 16 + r;                                  // 0..127
    colo[i] = (s & 1) * 64 + ((p & 63) ^ (((r >> 3) & 1) << 5));  // byte 0..127
  }
  const char* Ab = (const char*)A + (size_t)m0 * K2;
  const char* Bb = (const char*)W + (size_t)n0 * K2;
  char* lbase = (char*)lds;

#define STAGE_A(c, h, kt) do {                                                          \
    load16(Ab + (size_t)((h) * 128 + rowo[0]) * K2 + (size_t)(kt) * 128 + colo[0],      \
           lbase + (c) * 32768 + (h) * 16384 + tid * 16);                               \
    load16(Ab + (size_t)((h) * 128 + rowo[1]) * K2 + (size_t)(kt) * 128 + colo[1],      \
           lbase + (c) * 32768 + (h) * 16384 + 8192 + tid * 16);                        \
  } while (0)
#define STAGE_B(c, h, kt) do {                                                          \
    load16(Bb + (size_t)((h) * 128 + rowo[0]) * K2 + (size_t)(kt) * 128 + colo[0],      \
           lbase + 65536 + (c) * 32768 + (h) * 16384 + tid * 16);                       \
    load16(Bb + (size_t)((h) * 128 + rowo[1]) * K2 + (size_t)(kt) * 128 + colo[1],      \
           lbase + 65536 + (c) * 32768 + (h) * 16384 + 8192 + tid * 16);                \
  } while (0)

  const int foff = (fr * 64 + fq * 16) ^ (((fr >> 3) & 1) << 5);

  floatx4 acc[8][4];
#pragma unroll
  for (int i = 0; i < 8; i++)
#pragma unroll
    for (int j = 0; j < 4; j++) acc[i][j] = (floatx4){0.f, 0.f, 0.f, 0.f};

  // Prologue: K0 all 4 halves, then K1 {B0,B1,A0}. vmcnt(6) => K0 landed.
  STAGE_A(0, 0, 0); STAGE_A(0, 1, 0); STAGE_B(0, 0, 0); STAGE_B(0, 1, 0);
  STAGE_B(1, 0, 1); STAGE_B(1, 1, 1); STAGE_A(1, 0, 1);
  asm volatile("s_waitcnt vmcnt(6)");
  __builtin_amdgcn_sched_barrier(0);
  __builtin_amdgcn_s_barrier();

  const int NT = K >> 6;
  short8 av[8][2], bv[4][2];
#pragma unroll 2
  for (int t = 0; t < NT; ++t) {
    const int cur = t & 1, nxt = cur ^ 1;
    const char* la = lbase + cur * 32768 + wm * 16384 + foff;
    const char* lb = lbase + 65536 + cur * 32768 + (wn >> 1) * 16384 + (wn & 1) * 8192 + foff;

    // -- phase 1: all B frags + av[0,1]; stage A1(t+1)->nxt; drain; MFMA; BAR
#pragma unroll
    for (int nf = 0; nf < 4; nf++)
#pragma unroll
      for (int ks = 0; ks < 2; ks++)
        bv[nf][ks] = *(const short8*)(lb + (nf * 2 + ks) * 1024);
#pragma unroll
    for (int mf = 0; mf < 2; mf++)
#pragma unroll
      for (int ks = 0; ks < 2; ks++)
        av[mf][ks] = *(const short8*)(la + (mf * 2 + ks) * 1024);
    if (t + 1 < NT) STAGE_A(nxt, 1, t + 1);
    wait_lgkm0();
    cluster_mfma<EPI>(0, acc, av, bv);
    __builtin_amdgcn_s_barrier();

    // -- phase 2: av[2,3]; stage B0(t+2)->cur (B reads drained pre-BAR1)
#pragma unroll
    for (int mf = 2; mf < 4; mf++)
#pragma unroll
      for (int ks = 0; ks < 2; ks++)
        av[mf][ks] = *(const short8*)(la + (mf * 2 + ks) * 1024);
    if (t + 2 < NT) STAGE_B(cur, 0, t + 2);
    wait_lgkm0();
    cluster_mfma<EPI>(1, acc, av, bv);
    __builtin_amdgcn_s_barrier();

    // -- phase 3: av[4..7]; stage B1(t+2)->cur
#pragma unroll
    for (int mf = 4; mf < 8; mf++)
#pragma unroll
      for (int ks = 0; ks < 2; ks++)
        av[mf][ks] = *(const short8*)(la + (mf * 2 + ks) * 1024);
    if (t + 2 < NT) STAGE_B(cur, 1, t + 2);
    wait_lgkm0();
    cluster_mfma<EPI>(2, acc, av, bv);
    __builtin_amdgcn_s_barrier();

    // -- phase 4: no reads; stage A0(t+2)->cur (A reads drained pre-BAR3)
    if (t + 2 < NT) STAGE_A(cur, 0, t + 2);
    cluster_mfma<EPI>(3, acc, av, bv);
    // counted vmcnt once per K-tile: 3 newest half-tiles (6 loads) in flight.
    if (t < NT - 2) {
      asm volatile("s_waitcnt vmcnt(6)");
      __builtin_amdgcn_sched_barrier(0);
      __builtin_amdgcn_s_barrier();
    } else if (t == NT - 2) {
      asm volatile("s_waitcnt vmcnt(0)");
      __builtin_amdgcn_sched_barrier(0);
      __builtin_amdgcn_s_barrier();
    } // t == NT-1: epilogue touches only registers — no barrier needed
  }
#undef STAGE_A
#undef STAGE_B

#pragma unroll
  for (int mf = 0; mf < 8; mf++) {
#pragma unroll
    for (int nf = 0; nf < 4; nf++) {
#pragma unroll
      for (int r = 0; r < 4; r++) {
        const int gm = m0 + wm * 128 + mf * 16 + fq * 4 + r;
        const int gn = n0 + wn * 64 + nf * 16 + fr;
        const float v = acc[mf][nf][r];
        if constexpr (EPI == 0) {
          if (gn < 1024) outb0[(size_t)gm * 1024 + gn] = __float2bfloat16(v);
          else           outb1[(size_t)gm * 1024 + (gn - 1024)] = __float2bfloat16(v);
        } else {
          outf[(size_t)gm * N + gn] = v;
        }
      }
    }
  }
}

// ---------------------------------------------------------------------------
// x_proj GEMM, split-K x4: partial[kc][M,66] = u[M, kc-chunk] * xpw[66, kc-chunk]^T
// ---------------------------------------------------------------------------
__global__ __launch_bounds__(256) void gemm_xproj(
    const __hip_bfloat16* __restrict__ A,
    const __hip_bfloat16* __restrict__ W,
    float* __restrict__ part)
{
  constexpr int K = 1024, BK = 32, KC = K / XPJ_KS; // 256
  __shared__ short sA[128 * BK];
  __shared__ short sB[80 * BK];
  const int tid = threadIdx.x;
  const int wid = tid >> 6, lane = tid & 63;
  const int kc = blockIdx.x;
  const int m0 = blockIdx.y * 128;

  floatx4 acc[2][5];
#pragma unroll
  for (int i = 0; i < 2; i++)
#pragma unroll
    for (int j = 0; j < 5; j++) acc[i][j] = (floatx4){0.f, 0.f, 0.f, 0.f};

  const short* Ag = (const short*)A + (size_t)(m0 + (tid >> 2)) * K + kc * KC + (tid & 3) * 8;
  const int brow2 = 64 + (tid >> 2);
  const int brow2c = brow2 > 65 ? 65 : brow2;
  const short* Bg  = (const short*)W + (size_t)(tid >> 2) * K + kc * KC + (tid & 3) * 8;
  const short* Bg2 = (const short*)W + (size_t)brow2c * K + kc * KC + (tid & 3) * 8;
  const size_t rstep = (size_t)64 * K;
  const int fr = lane & 15, fq = lane >> 4;

  for (int kb = 0; kb < KC; kb += BK) {
    load16(Ag, &sA[tid * 8]);
    load16(Ag + rstep, &sA[2048 + tid * 8]);
    load16(Bg, &sB[tid * 8]);
    if (tid < 64) load16(Bg2, &sB[2048 + tid * 8]);
    Ag += BK; Bg += BK; Bg2 += BK;
    __syncthreads();

    short8 av[2], bv[5];
#pragma unroll
    for (int mt = 0; mt < 2; mt++) av[mt] = *(const short8*)&sA[(wid * 32 + mt * 16 + fr) * BK + fq * 8];
#pragma unroll
    for (int nt = 0; nt < 5; nt++) bv[nt] = *(const short8*)&sB[(nt * 16 + fr) * BK + fq * 8];
#pragma unroll
    for (int mt = 0; mt < 2; mt++)
#pragma unroll
      for (int nt = 0; nt < 5; nt++)
        acc[mt][nt] = __builtin_amdgcn_mfma_f32_16x16x32_bf16(av[mt], bv[nt], acc[mt][nt], 0, 0, 0);
    __syncthreads();
  }

  float* pp = part + (size_t)kc * Mrows * 66;
#pragma unroll
  for (int mt = 0; mt < 2; mt++) {
#pragma unroll
    for (int nt = 0; nt < 5; nt++) {
#pragma unroll
      for (int r = 0; r < 4; r++) {
        const int gm = m0 + wid * 32 + mt * 16 + fq * 4 + r;
        const int gn = nt * 16 + fr;
        if (gn < 66) pp[(size_t)gm * 66 + gn] = acc[mt][nt][r];
      }
    }
  }
}

__global__ __launch_bounds__(256) void xproj_reduce(
    const float* __restrict__ part,
    __hip_bfloat16* __restrict__ dts,
    float* __restrict__ Bs, float* __restrict__ Cs)
{
  const int i = blockIdx.x * 256 + threadIdx.x;
  if (i >= Mrows * 66) return;
  const int gm = i / 66, gn = i - gm * 66;
  float s = part[i] + part[i + (size_t)Mrows * 66]
          + part[i + (size_t)2 * Mrows * 66] + part[i + (size_t)3 * Mrows * 66];
  if (gn < 64)       dts[(size_t)gm * 64 + gn] = __float2bfloat16(s);
  else if (gn == 64) Bs[gm] = s;
  else               Cs[gm] = s;
}

// ---------------------------------------------------------------------------
// Causal depthwise conv (k=2) + bias + SiLU.  Vectorized: 8 d-elems/thread.
// ---------------------------------------------------------------------------
__global__ __launch_bounds__(256) void conv_silu(
    const __hip_bfloat16* __restrict__ xc, const float* __restrict__ cw,
    const float* __restrict__ cb, __hip_bfloat16* __restrict__ u)
{
  const size_t i8 = ((size_t)blockIdx.x * 256 + threadIdx.x) * 8;
  const int d8 = (int)(i8 & (Di - 1));
  const int l  = (int)((i8 >> 10) & (Lz - 1));
  const short8 cur = *(const short8*)((const short*)xc + i8);
  short8 prv;
  if (l > 0) prv = *(const short8*)((const short*)xc + i8 - Di);
  else       prv = (short8){0, 0, 0, 0, 0, 0, 0, 0};
  const float4* cw4 = (const float4*)(cw + 2 * d8);
  const float4 wA = cw4[0], wB = cw4[1], wC = cw4[2], wD = cw4[3];
  const float w0a[8] = {wA.x, wA.z, wB.x, wB.z, wC.x, wC.z, wD.x, wD.z};
  const float w1a[8] = {wA.y, wA.w, wB.y, wB.w, wC.y, wC.w, wD.y, wD.w};
  const float4* cb4 = (const float4*)(cb + d8);
  const float4 b0 = cb4[0], b1 = cb4[1];
  const float ba[8] = {b0.x, b0.y, b0.z, b0.w, b1.x, b1.y, b1.z, b1.w};
  short8 out;
#pragma unroll
  for (int k = 0; k < 8; k++) {
    const float pc = __uint_as_float(((uint32_t)(uint16_t)prv[k]) << 16);
    const float cc = __uint_as_float(((uint32_t)(uint16_t)cur[k]) << 16);
    const float v = pc * w0a[k] + cc * w1a[k] + ba[k];
    const float s = v / (1.f + __expf(-v));
    out[k] = f2bfs(s);
  }
  *(short8*)((short*)u + i8) = out;
}

// ---------------------------------------------------------------------------
// Chunked scan, D_STATE=1:  h[l] = exp(delta*A)*h[l-1] + delta*Bs*u
// CH=32 (1024 wg for p1/p3 = 4 waves/SIMD), 2 d's/thread (4B loads).
// ---------------------------------------------------------------------------
__global__ __launch_bounds__(256) void scan_p1(
    const __hip_bfloat16* __restrict__ delta, const __hip_bfloat16* __restrict__ u,
    const float* __restrict__ Bsv, const float* __restrict__ A_logs,
    float* __restrict__ carryP, float* __restrict__ carryS)
{
  const int dp = blockIdx.x * 256 + threadIdx.x;   // d-pair 0..511
  const int d  = dp * 2;
  const int c = blockIdx.y, b = blockIdx.z;
  const float2 Al = *(const float2*)(A_logs + d);
  const float Ac0 = -__expf(Al.x), Ac1 = -__expf(Al.y);
  const size_t base = ((size_t)(b * Lz + c * CH)) * Di + d;
  const float* Bp = Bsv + (size_t)b * Lz + c * CH;
  float P0 = 1.f, h0 = 0.f, P1 = 1.f, h1 = 0.f;
#pragma unroll 8
  for (int j = 0; j < CH; j++) {
    const uint32_t dv = *(const uint32_t*)((const uint16_t*)delta + base + (size_t)j * Di);
    const uint32_t uv = *(const uint32_t*)((const uint16_t*)u + base + (size_t)j * Di);
    const float dl0 = __uint_as_float(dv << 16);
    const float dl1 = __uint_as_float(dv & 0xffff0000u);
    const float uu0 = __uint_as_float(uv << 16);
    const float uu1 = __uint_as_float(uv & 0xffff0000u);
    const float bj  = Bp[j];
    const float a0 = __expf(dl0 * Ac0), a1 = __expf(dl1 * Ac1);
    h0 = a0 * h0 + dl0 * bj * uu0;
    h1 = a1 * h1 + dl1 * bj * uu1;
    P0 *= a0; P1 *= a1;
  }
  const size_t ci = ((size_t)(b * NCH + c)) * Di + d;
  *(float2*)(carryP + ci) = make_float2(P0, P1);
  *(float2*)(carryS + ci) = make_float2(h0, h1);
}

__global__ __launch_bounds__(64) void scan_p2(
    const float* __restrict__ carryP, const float* __restrict__ carryS,
    float* __restrict__ hin)
{
  const int t = blockIdx.x * 64 + threadIdx.x;   // 0..4095
  const int b = t >> 10, d = t & (Di - 1);
  float h = 0.f;
  for (int c = 0; c < NCH; c++) {
    const size_t ci = ((size_t)(b * NCH + c)) * Di + d;
    hin[ci] = h;
    h = carryP[ci] * h + carryS[ci];
  }
}

__global__ __launch_bounds__(256) void scan_p3(
    const __hip_bfloat16* __restrict__ delta, __hip_bfloat16* __restrict__ uy,
    const float* __restrict__ Bsv, const float* __restrict__ Csv,
    const float* __restrict__ A_logs, const float* __restrict__ Ds,
    const float* __restrict__ hin)
{
  const int dp = blockIdx.x * 256 + threadIdx.x;
  const int d  = dp * 2;
  const int c = blockIdx.y, b = blockIdx.z;
  const float2 Al = *(const float2*)(A_logs + d);
  const float Ac0 = -__expf(Al.x), Ac1 = -__expf(Al.y);
  const float2 Dd = *(const float2*)(Ds + d);
  const size_t base = ((size_t)(b * Lz + c * CH)) * Di + d;
  const float* Bp = Bsv + (size_t)b * Lz + c * CH;
  const float* Cp = Csv + (size_t)b * Lz + c * CH;
  const size_t ci = ((size_t)(b * NCH + c)) * Di + d;
  const float2 hh = *(const float2*)(hin + ci);
  float h0 = hh.x, h1 = hh.y;
#pragma unroll 8
  for (int j = 0; j < CH; j++) {
    const size_t ix = base + (size_t)j * Di;
    const uint32_t dv = *(const uint32_t*)((const uint16_t*)delta + ix);
    const uint32_t uv = *(const uint32_t*)((const uint16_t*)uy + ix);
    const float dl0 = __uint_as_float(dv << 16);
    const float dl1 = __uint_as_float(dv & 0xffff0000u);
    const float uu0 = __uint_as_float(uv << 16);
    const float uu1 = __uint_as_float(uv & 0xffff0000u);
    const float bj = Bp[j], cj = Cp[j];
    const float a0 = __expf(dl0 * Ac0), a1 = __expf(dl1 * Ac1);
    h0 = a0 * h0 + dl0 * bj * uu0;
    h1 = a1 * h1 + dl1 * bj * uu1;
    const float y0 = h0 * cj + uu0 * Dd.x;
    const float y1 = h1 * cj + uu1 * Dd.y;
    const uint32_t o = (uint32_t)(uint16_t)f2bfs(y0) | ((uint32_t)(uint16_t)f2bfs(y1) << 16);
    *(uint32_t*)((uint16_t*)uy + ix) = o;
  }
}

// ---------------------------------------------------------------------------
// LayerNorm over D=1024 + SiLU(z) gate -> bf16.  z-load and store vectorized.
// ---------------------------------------------------------------------------
__global__ __launch_bounds__(256) void ln_gate(
    const __hip_bfloat16* __restrict__ y, const __hip_bfloat16* __restrict__ z,
    const float* __restrict__ lnw, const float* __restrict__ lnb,
    __hip_bfloat16* __restrict__ yg)
{
  const int row = blockIdx.x;
  const int tid = threadIdx.x;
  const int wid = tid >> 6, lane = tid & 63;
  const short4v yv = *(const short4v*)((const short*)y + (size_t)row * Di + tid * 4);
  const short4v zv4 = *(const short4v*)((const short*)z + (size_t)row * Di + tid * 4);
  float v[4];
#pragma unroll
  for (int i = 0; i < 4; i++)
    v[i] = __uint_as_float(((uint32_t)(uint16_t)yv[i]) << 16);
  float s1 = v[0] + v[1] + v[2] + v[3];
  float s2 = v[0] * v[0] + v[1] * v[1] + v[2] * v[2] + v[3] * v[3];
#pragma unroll
  for (int o = 32; o > 0; o >>= 1) {
    s1 += __shfl_down(s1, o, 64);
    s2 += __shfl_down(s2, o, 64);
  }
  __shared__ float r1[4], r2[4];
  if (lane == 0) { r1[wid] = s1; r2[wid] = s2; }
  __syncthreads();
  const float t1 = r1[0] + r1[1] + r1[2] + r1[3];
  const float t2 = r2[0] + r2[1] + r2[2] + r2[3];
  const float mu = t1 * (1.f / Di);
  const float var = t2 * (1.f / Di) - mu * mu;
  const float rstd = rsqrtf(var + 1e-5f);

  const float4 wv = ((const float4*)lnw)[tid];
  const float4 bv = ((const float4*)lnb)[tid];
  const float wa[4] = {wv.x, wv.y, wv.z, wv.w};
  const float ba[4] = {bv.x, bv.y, bv.z, bv.w};
  short4v og;
#pragma unroll
  for (int i = 0; i < 4; i++) {
    const float zz = __uint_as_float(((uint32_t)(uint16_t)zv4[i]) << 16);
    const float g = zz / (1.f + __expf(-zz));
    og[i] = f2bfs(((v[i] - mu) * rstd * wa[i] + ba[i]) * g);
  }
  *(short4v*)((short*)yg + (size_t)row * Di + tid * 4) = og;
}

// ---------------------------------------------------------------------------
// Diagnostic: fill d_out (f32) with ws_size expressed in KiB (read via absmax).
// ---------------------------------------------------------------------------
__global__ __launch_bounds__(256) void fill_diag(float* __restrict__ out, int n, float val)
{
  const int i = blockIdx.x * 256 + threadIdx.x;
  if (i < n) out[i] = val;
}

// ---------------------------------------------------------------------------
extern "C" void kernel_launch(void* const* d_in, const int* in_sizes, int n_in,
                              void* d_out, int out_size, void* d_ws, size_t ws_size,
                              hipStream_t stream)
{
  const float* x      = (const float*)d_in[0];
  const float* w_in   = (const float*)d_in[1];
  const float* conv_w = (const float*)d_in[2];
  const float* conv_b = (const float*)d_in[3];
  const float* xpw    = (const float*)d_in[4];
  const float* dtw    = (const float*)d_in[5];
  const float* dtb    = (const float*)d_in[6];
  const float* A_logs = (const float*)d_in[7];
  const float* Ds     = (const float*)d_in[8];
  const float* lnw    = (const float*)d_in[9];
  const float* lnb    = (const float*)d_in[10];
  const float* w_out  = (const float*)d_in[11];
  float* outF = (float*)d_out;   // 16.7M f32 = 64 MiB

  const size_t BF16BIG  = (size_t)Mrows * Di * sizeof(__hip_bfloat16); // 32 MiB
  const size_t NEED_RUN = 69603328;  // exact ws usage below (unchanged)

  if (ws_size < NEED_RUN) {
    fill_diag<<<(out_size + 255) / 256, 256, 0, stream>>>(
        outF, out_size, (float)(ws_size >> 10));
    return;
  }

  uint8_t* ws = (uint8_t*)d_ws;
  size_t off = 0;
  auto alloc = [&](size_t bytes) { void* p = ws + off; off += (bytes + 255) & ~(size_t)255; return p; };

  // ws layout (66.4 MiB total):
  __hip_bfloat16* slotA    = (__hip_bfloat16*)alloc(BF16BIG);   // xc -> delta -> yg
  __hip_bfloat16* slotC    = (__hip_bfloat16*)alloc(BF16BIG);   // xbf -> u -> y (in-place)
  __hip_bfloat16* w_out_bf = (__hip_bfloat16*)alloc((size_t)Dm * Di * 2);
  __hip_bfloat16* xpw_bf   = (__hip_bfloat16*)alloc((size_t)66 * Di * 2);
  __hip_bfloat16* dtw_bf   = (__hip_bfloat16*)alloc((size_t)Di * 64 * 2);
  float* Bsv = (float*)alloc((size_t)Mrows * sizeof(float));
  float* Csv = (float*)alloc((size_t)Mrows * sizeof(float));

  // d_out (64 MiB f32) doubles as scratch for regions dead before stage 9:
  //  [0,32M):  z (alive until stage 8)
  //  [32,36M): w_in_bf (dead after stage 1)
  //  [36,38M): dts (bf16, dead after stage 4)
  //  [38,40M): carryP (2MB, written stage 5)
  //  [40,42M): carryS (2MB; overlaps xpj_part head — dead after stage 3)
  //  [42,44M): hin    (2MB; ditto)
  //  [40M,57.3M): xpj_part (f32, dead after stage 3)
  __hip_bfloat16* zbuf    = (__hip_bfloat16*)d_out;
  __hip_bfloat16* w_in_bf = (__hip_bfloat16*)((uint8_t*)d_out + 33554432);
  __hip_bfloat16* dts     = (__hip_bfloat16*)((uint8_t*)d_out + 37748736);
  float* carryP = (float*)((uint8_t*)d_out + 39845888);
  float* carryS = (float*)((uint8_t*)d_out + 41943040);
  float* hin    = (float*)((uint8_t*)d_out + 44040192);
  float* xpj_part = (float*)((uint8_t*)d_out + 41943040);  // overlaps carryS/hin (dead by scan)

  __hip_bfloat16* xbf   = slotC;   // dead after stage 1 (overwritten by u)
  __hip_bfloat16* xcbuf = slotA;
  __hip_bfloat16* ubuf  = slotC;
  __hip_bfloat16* delta = slotA;   // overwrites xc (dead after conv)
  __hip_bfloat16* yg    = slotA;   // overwrites delta (dead after scan_p3)

  // 0. convert f32 inputs -> bf16 working copies (one fused launch)
  cvt_all<<<(5014016 + 255) / 256, 256, 0, stream>>>(
      x, w_in, w_out, xpw, dtw, xbf, w_in_bf, w_out_bf, xpw_bf, dtw_bf);

  // 1. xz = x @ w_in^T -> xc (slotA), z (d_out[0,32M))  [256^2 4-phase]
  gemm256<0><<<dim3(2 * Di / 256, Mrows / 256), 512, 0, stream>>>(
      xbf, w_in_bf, Dm, 2 * Di, xcbuf, zbuf, nullptr);
  // 2. conv + silu -> u (slotC; xbf dead)
  conv_silu<<<(Mrows * Di / 8) / 256, 256, 0, stream>>>(xcbuf, conv_w, conv_b, ubuf);
  // 3. x_proj split-K -> partials -> reduce to dts, Bs, Cs
  gemm_xproj<<<dim3(XPJ_KS, Mrows / 128), 256, 0, stream>>>(ubuf, xpw_bf, xpj_part);
  xproj_reduce<<<(Mrows * 66 + 255) / 256, 256, 0, stream>>>(xpj_part, dts, Bsv, Csv);
  // 4. delta = softplus(dts @ dtw^T + bias) -> slotA (xc dead)  [K=64, mem-bound]
  gemm128<1><<<dim3(Di / 128, Mrows / 128), 256, 0, stream>>>(
      dts, dtw_bf, 64, Di, delta, nullptr, nullptr, dtb);
  // 5-7. chunked scan (CH=32); y written in-place over u
  scan_p1<<<dim3(Di / 512, NCH, Bz), 256, 0, stream>>>(delta, ubuf, Bsv, A_logs, carryP, carryS);
  scan_p2<<<(Bz * Di) / 64, 64, 0, stream>>>(carryP, carryS, hin);
  scan_p3<<<dim3(Di / 512, NCH, Bz), 256, 0, stream>>>(delta, ubuf, Bsv, Csv, A_logs, Ds, hin);
  // 8. layernorm + silu(z) gate -> yg (slotA; delta dead)
  ln_gate<<<Mrows, 256, 0, stream>>>(ubuf, zbuf, lnw, lnb, yg);
  // 9. out = yg @ w_out^T -> d_out f32 (overwrites all d_out scratch — dead)
  gemm256<1><<<dim3(Dm / 256, Mrows / 256), 512, 0, stream>>>(
      yg, w_out_bf, Di, Dm, nullptr, nullptr, outF);
}

// Round 8
// 351.208 us; speedup vs baseline: 1.1691x; 1.0020x over previous
//
#include <hip/hip_runtime.h>
#include <hip/hip_bf16.h>
#include <cstdint>
#include <cstddef>

typedef short short8 __attribute__((ext_vector_type(8)));
typedef short short4v __attribute__((ext_vector_type(4)));
typedef float floatx4 __attribute__((ext_vector_type(4)));

constexpr int Bz = 4;
constexpr int Lz = 4096;
constexpr int Dm = 1024;       // d_model
constexpr int Di = 1024;       // d_inner
constexpr int Mrows = Bz * Lz; // 16384
constexpr int CH  = 32;        // scan chunk length
constexpr int NCH = Lz / CH;   // 128
constexpr int XPJ_KS = 4;      // x_proj split-K factor

__device__ __forceinline__ void load16(const void* g, void* l) {
  __builtin_amdgcn_global_load_lds((__attribute__((address_space(1))) void*)g,
                                   (__attribute__((address_space(3))) void*)l,
                                   16, 0, 0);
}

__device__ __forceinline__ float bf2f(const __hip_bfloat16 v) { return __bfloat162float(v); }
__device__ __forceinline__ short f2bfs(float v) {
  __hip_bfloat16 h = __float2bfloat16(v);
  return *(short*)&h;
}

// ---------------------------------------------------------------------------
// All f32->bf16 conversions (x + 4 weight matrices) in ONE launch.
// ---------------------------------------------------------------------------
__global__ __launch_bounds__(256) void cvt_all(
    const float* __restrict__ x, const float* __restrict__ w_in,
    const float* __restrict__ w_out, const float* __restrict__ xpw,
    const float* __restrict__ dtw,
    __hip_bfloat16* __restrict__ xbf, __hip_bfloat16* __restrict__ w_in_bf,
    __hip_bfloat16* __restrict__ w_out_bf, __hip_bfloat16* __restrict__ xpw_bf,
    __hip_bfloat16* __restrict__ dtw_bf)
{
  const int i = blockIdx.x * 256 + threadIdx.x;
  const float* src; __hip_bfloat16* dst; int j;
  if (i < 4194304)      { src = x;     dst = xbf;      j = i; }            // 16M elems
  else if (i < 4718592) { src = w_in;  dst = w_in_bf;  j = i - 4194304; }  // 2M
  else if (i < 4980736) { src = w_out; dst = w_out_bf; j = i - 4718592; }  // 1M
  else if (i < 4997632) { src = xpw;   dst = xpw_bf;   j = i - 4980736; }  // 66K
  else if (i < 5014016) { src = dtw;   dst = dtw_bf;   j = i - 4997632; }  // 64K
  else return;
  const float4 v = ((const float4*)src)[j];
  short4v s;
  s[0] = f2bfs(v.x); s[1] = f2bfs(v.y); s[2] = f2bfs(v.z); s[3] = f2bfs(v.w);
  ((short4v*)dst)[j] = s;
}

// ---------------------------------------------------------------------------
// 128x128 MFMA GEMM (m97-class structure). Retained ONLY for the K=64
// delta GEMM (EPI 1), which is memory-bound.
// ---------------------------------------------------------------------------
template <int EPI>
__global__ __launch_bounds__(256) void gemm128(
    const __hip_bfloat16* __restrict__ A,
    const __hip_bfloat16* __restrict__ W,
    int K, int N,
    __hip_bfloat16* __restrict__ outb0,
    __hip_bfloat16* __restrict__ outb1,
    float* __restrict__ outf,
    const float* __restrict__ biasf)
{
  constexpr int BK = 32;
  constexpr int GY = 16;
  __shared__ short sA[128 * BK];
  __shared__ short sB[128 * BK];
  const int tid  = threadIdx.x;
  const int wid  = tid >> 6;
  const int lane = tid & 63;

  const int gx  = gridDim.x;
  const int id  = blockIdx.y * gx + blockIdx.x;
  const int seg = gx * GY;
  const int bx  = (id % seg) / GY;
  const int by  = (id / seg) * GY + (id % GY);

  const int m0 = by * 128;
  const int n0 = bx * 128;
  const int wm = (wid & 1) * 64;
  const int wn = (wid >> 1) * 64;

  floatx4 acc[4][4];
#pragma unroll
  for (int i = 0; i < 4; i++)
#pragma unroll
    for (int j = 0; j < 4; j++) acc[i][j] = (floatx4){0.f, 0.f, 0.f, 0.f};

  const short* Ag = (const short*)A + (size_t)(m0 + (tid >> 2)) * K + (tid & 3) * 8;
  const short* Bg = (const short*)W + (size_t)(n0 + (tid >> 2)) * K + (tid & 3) * 8;
  short* sAd = &sA[tid * 8];
  short* sBd = &sB[tid * 8];
  const size_t rstep = (size_t)64 * K;
  const int fr = lane & 15, fq = lane >> 4;

  for (int kb = 0; kb < K; kb += BK) {
    load16(Ag, sAd);
    load16(Ag + rstep, sAd + 2048);
    load16(Bg, sBd);
    load16(Bg + rstep, sBd + 2048);
    Ag += BK; Bg += BK;
    __syncthreads();

    short8 av[4], bv[4];
#pragma unroll
    for (int mt = 0; mt < 4; mt++) av[mt] = *(const short8*)&sA[(wm + mt * 16 + fr) * BK + fq * 8];
#pragma unroll
    for (int nt = 0; nt < 4; nt++) bv[nt] = *(const short8*)&sB[(wn + nt * 16 + fr) * BK + fq * 8];
#pragma unroll
    for (int mt = 0; mt < 4; mt++)
#pragma unroll
      for (int nt = 0; nt < 4; nt++)
        acc[mt][nt] = __builtin_amdgcn_mfma_f32_16x16x32_bf16(av[mt], bv[nt], acc[mt][nt], 0, 0, 0);
    __syncthreads();
  }

#pragma unroll
  for (int mt = 0; mt < 4; mt++) {
#pragma unroll
    for (int nt = 0; nt < 4; nt++) {
#pragma unroll
      for (int r = 0; r < 4; r++) {
        const int gm = m0 + wm + mt * 16 + fq * 4 + r;
        const int gn = n0 + wn + nt * 16 + fr;
        float v = acc[mt][nt][r];
        if constexpr (EPI == 0) {
          if (gn < 1024) outb0[(size_t)gm * 1024 + gn] = __float2bfloat16(v);
          else           outb1[(size_t)gm * 1024 + (gn - 1024)] = __float2bfloat16(v);
        } else if constexpr (EPI == 1) {
          v += biasf[gn];
          v = (v > 15.f) ? v : __logf(1.f + __expf(v));
          outb0[(size_t)gm * N + gn] = __float2bfloat16(v);
        } else {
          outf[(size_t)gm * N + gn] = v;
        }
      }
    }
  }
}

// ---------------------------------------------------------------------------
// 256x256 4-phase MFMA GEMM (verified round-7 K-loop, UNCHANGED).
// ROUND-8 CHANGE (epilogue only): EPI==0 xc-half blocks fuse conv+SiLU:
//   acc -> LDS bf16 [256][256] (LDS idle after K-loop: last-iter reads drain
//   at ph3-end barrier, ph4 touches no LDS, vmcnt(0)@NT-2 drained stages)
//   -> __syncthreads -> conv from rows r/r-1 -> u to global (16B coalesced).
// xc never touches HBM (-64 MB round-trip + one kernel). Tile-boundary rows
// (predecessor in another block) -> first/last xc rows to edge buffers;
// conv_fix kernel (launched after) fills u rows m0 of each tile.
// ---------------------------------------------------------------------------
__device__ __forceinline__ void wait_lgkm0() {
  asm volatile("s_waitcnt lgkmcnt(0)");
  __builtin_amdgcn_sched_barrier(0);
}

template <int EPI>
__device__ __forceinline__ void cluster_mfma(int MQ, floatx4 (&acc)[8][4],
                                             const short8 (&av)[8][2],
                                             const short8 (&bv)[4][2])
{
  __builtin_amdgcn_s_setprio(1);
#pragma unroll
  for (int j = 0; j < 2; j++)
#pragma unroll
    for (int nf = 0; nf < 4; nf++)
#pragma unroll
      for (int ks = 0; ks < 2; ks++)
        acc[2 * MQ + j][nf] = __builtin_amdgcn_mfma_f32_16x16x32_bf16(
            av[2 * MQ + j][ks], bv[nf][ks], acc[2 * MQ + j][nf], 0, 0, 0);
  __builtin_amdgcn_s_setprio(0);
}

template <int EPI>
__global__ __launch_bounds__(512, 2) void gemm256(
    const __hip_bfloat16* __restrict__ A,
    const __hip_bfloat16* __restrict__ W,
    int K, int N,
    __hip_bfloat16* __restrict__ outb0,   // EPI0: u (fused conv out). EPI1: bf16 out
    __hip_bfloat16* __restrict__ outb1,   // EPI0: z
    float* __restrict__ outf,             // EPI1: f32 out
    const float* __restrict__ cw, const float* __restrict__ cb,
    __hip_bfloat16* __restrict__ xef, __hip_bfloat16* __restrict__ xel)
{
  __shared__ alignas(16) char lds[131072];
  const int tid  = threadIdx.x;
  const int wid  = tid >> 6;
  const int lane = tid & 63;
  const int wm = wid >> 2;      // 0..1
  const int wn = wid & 3;       // 0..3
  const int fr = lane & 15, fq = lane >> 4;

  // Bijective XCD swizzle (nwg % 8 == 0 for all launches here).
  const int gx   = gridDim.x;
  const int nwg  = gx * gridDim.y;
  const int orig = blockIdx.y * gx + blockIdx.x;
  const int swz  = (orig & 7) * (nwg >> 3) + (orig >> 3);
  const int bx   = swz % gx;
  const int by   = swz / gx;
  const int m0 = by * 256;
  const int n0 = bx * 256;
  const size_t K2 = (size_t)K * 2;   // row bytes

  int rowo[2], colo[2];
#pragma unroll
  for (int i = 0; i < 2; i++) {
    const int p = i * 8192 + tid * 16;
    const int s = p >> 10;           // subtile 0..15 (rb*2+cb)
    const int r = (p >> 6) & 15;     // row within subtile
    rowo[i] = (s >> 1) * 16 + r;                                  // 0..127
    colo[i] = (s & 1) * 64 + ((p & 63) ^ (((r >> 3) & 1) << 5));  // byte 0..127
  }
  const char* Ab = (const char*)A + (size_t)m0 * K2;
  const char* Bb = (const char*)W + (size_t)n0 * K2;
  char* lbase = (char*)lds;

#define STAGE_A(c, h, kt) do {                                                          \
    load16(Ab + (size_t)((h) * 128 + rowo[0]) * K2 + (size_t)(kt) * 128 + colo[0],      \
           lbase + (c) * 32768 + (h) * 16384 + tid * 16);                               \
    load16(Ab + (size_t)((h) * 128 + rowo[1]) * K2 + (size_t)(kt) * 128 + colo[1],      \
           lbase + (c) * 32768 + (h) * 16384 + 8192 + tid * 16);                        \
  } while (0)
#define STAGE_B(c, h, kt) do {                                                          \
    load16(Bb + (size_t)((h) * 128 + rowo[0]) * K2 + (size_t)(kt) * 128 + colo[0],      \
           lbase + 65536 + (c) * 32768 + (h) * 16384 + tid * 16);                       \
    load16(Bb + (size_t)((h) * 128 + rowo[1]) * K2 + (size_t)(kt) * 128 + colo[1],      \
           lbase + 65536 + (c) * 32768 + (h) * 16384 + 8192 + tid * 16);                \
  } while (0)

  const int foff = (fr * 64 + fq * 16) ^ (((fr >> 3) & 1) << 5);

  floatx4 acc[8][4];
#pragma unroll
  for (int i = 0; i < 8; i++)
#pragma unroll
    for (int j = 0; j < 4; j++) acc[i][j] = (floatx4){0.f, 0.f, 0.f, 0.f};

  // Prologue: K0 all 4 halves, then K1 {B0,B1,A0}. vmcnt(6) => K0 landed.
  STAGE_A(0, 0, 0); STAGE_A(0, 1, 0); STAGE_B(0, 0, 0); STAGE_B(0, 1, 0);
  STAGE_B(1, 0, 1); STAGE_B(1, 1, 1); STAGE_A(1, 0, 1);
  asm volatile("s_waitcnt vmcnt(6)");
  __builtin_amdgcn_sched_barrier(0);
  __builtin_amdgcn_s_barrier();

  const int NT = K >> 6;
  short8 av[8][2], bv[4][2];
#pragma unroll 2
  for (int t = 0; t < NT; ++t) {
    const int cur = t & 1, nxt = cur ^ 1;
    const char* la = lbase + cur * 32768 + wm * 16384 + foff;
    const char* lb = lbase + 65536 + cur * 32768 + (wn >> 1) * 16384 + (wn & 1) * 8192 + foff;

    // -- phase 1: all B frags + av[0,1]; stage A1(t+1)->nxt; drain; MFMA; BAR
#pragma unroll
    for (int nf = 0; nf < 4; nf++)
#pragma unroll
      for (int ks = 0; ks < 2; ks++)
        bv[nf][ks] = *(const short8*)(lb + (nf * 2 + ks) * 1024);
#pragma unroll
    for (int mf = 0; mf < 2; mf++)
#pragma unroll
      for (int ks = 0; ks < 2; ks++)
        av[mf][ks] = *(const short8*)(la + (mf * 2 + ks) * 1024);
    if (t + 1 < NT) STAGE_A(nxt, 1, t + 1);
    wait_lgkm0();
    cluster_mfma<EPI>(0, acc, av, bv);
    __builtin_amdgcn_s_barrier();

    // -- phase 2: av[2,3]; stage B0(t+2)->cur (B reads drained pre-BAR1)
#pragma unroll
    for (int mf = 2; mf < 4; mf++)
#pragma unroll
      for (int ks = 0; ks < 2; ks++)
        av[mf][ks] = *(const short8*)(la + (mf * 2 + ks) * 1024);
    if (t + 2 < NT) STAGE_B(cur, 0, t + 2);
    wait_lgkm0();
    cluster_mfma<EPI>(1, acc, av, bv);
    __builtin_amdgcn_s_barrier();

    // -- phase 3: av[4..7]; stage B1(t+2)->cur
#pragma unroll
    for (int mf = 4; mf < 8; mf++)
#pragma unroll
      for (int ks = 0; ks < 2; ks++)
        av[mf][ks] = *(const short8*)(la + (mf * 2 + ks) * 1024);
    if (t + 2 < NT) STAGE_B(cur, 1, t + 2);
    wait_lgkm0();
    cluster_mfma<EPI>(2, acc, av, bv);
    __builtin_amdgcn_s_barrier();

    // -- phase 4: no reads; stage A0(t+2)->cur (A reads drained pre-BAR3)
    if (t + 2 < NT) STAGE_A(cur, 0, t + 2);
    cluster_mfma<EPI>(3, acc, av, bv);
    if (t < NT - 2) {
      asm volatile("s_waitcnt vmcnt(6)");
      __builtin_amdgcn_sched_barrier(0);
      __builtin_amdgcn_s_barrier();
    } else if (t == NT - 2) {
      asm volatile("s_waitcnt vmcnt(0)");
      __builtin_amdgcn_sched_barrier(0);
      __builtin_amdgcn_s_barrier();
    } // t == NT-1: epilogue follows; LDS reads/stages all drained (see header)
  }
#undef STAGE_A
#undef STAGE_B

  if constexpr (EPI == 0) {
    if (n0 < 1024) {
      // ---- fused conv+SiLU epilogue (xc-half blocks) ----
      short* lt = (short*)lds;
#pragma unroll
      for (int mf = 0; mf < 8; mf++)
#pragma unroll
        for (int nf = 0; nf < 4; nf++)
#pragma unroll
          for (int r = 0; r < 4; r++)
            lt[(wm * 128 + mf * 16 + fq * 4 + r) * 256 + wn * 64 + nf * 16 + fr] =
                f2bfs(acc[mf][nf][r]);
      __syncthreads();

      const int lrow0 = wid * 2 + (lane >> 5);   // wave covers 2 rows/iter
      const int c8 = (lane & 31) * 8;            // 8-col chunk, coalesced
      const int d0 = n0 + c8;
      const float4* cw4 = (const float4*)(cw + 2 * d0);
      const float4 wA = cw4[0], wB = cw4[1], wC = cw4[2], wD = cw4[3];
      const float w0a[8] = {wA.x, wA.z, wB.x, wB.z, wC.x, wC.z, wD.x, wD.z};
      const float w1a[8] = {wA.y, wA.w, wB.y, wB.w, wC.y, wC.w, wD.y, wD.w};
      const float4* cb4 = (const float4*)(cb + d0);
      const float4 b0 = cb4[0], b1 = cb4[1];
      const float ba[8] = {b0.x, b0.y, b0.z, b0.w, b1.x, b1.y, b1.z, b1.w};
      const int tix = m0 >> 8;

      for (int it = 0; it < 16; ++it) {
        const int rl = lrow0 + it * 16;
        const short8 curv = *(const short8*)&lt[rl * 256 + c8];
        if (rl == 0)   *(short8*)((short*)xef + tix * 1024 + d0) = curv;
        if (rl == 255) *(short8*)((short*)xel + tix * 1024 + d0) = curv;
        if (rl == 0) continue;   // boundary row: conv_fix fills u[m0]
        const short8 prvv = *(const short8*)&lt[(rl - 1) * 256 + c8];
        short8 outv;
#pragma unroll
        for (int k = 0; k < 8; k++) {
          const float pc = __uint_as_float(((uint32_t)(uint16_t)prvv[k]) << 16);
          const float cc = __uint_as_float(((uint32_t)(uint16_t)curv[k]) << 16);
          const float v = pc * w0a[k] + cc * w1a[k] + ba[k];
          outv[k] = f2bfs(v / (1.f + __expf(-v)));
        }
        *(short8*)((short*)outb0 + (size_t)(m0 + rl) * 1024 + d0) = outv;
      }
    } else {
      // ---- z-half blocks: direct write ----
#pragma unroll
      for (int mf = 0; mf < 8; mf++)
#pragma unroll
        for (int nf = 0; nf < 4; nf++)
#pragma unroll
          for (int r = 0; r < 4; r++) {
            const int gm = m0 + wm * 128 + mf * 16 + fq * 4 + r;
            const int gn = n0 + wn * 64 + nf * 16 + fr;
            outb1[(size_t)gm * 1024 + (gn - 1024)] = __float2bfloat16(acc[mf][nf][r]);
          }
    }
  } else {
#pragma unroll
    for (int mf = 0; mf < 8; mf++)
#pragma unroll
      for (int nf = 0; nf < 4; nf++)
#pragma unroll
        for (int r = 0; r < 4; r++) {
          const int gm = m0 + wm * 128 + mf * 16 + fq * 4 + r;
          const int gn = n0 + wn * 64 + nf * 16 + fr;
          outf[(size_t)gm * N + gn] = acc[mf][nf][r];
        }
  }
}

// ---------------------------------------------------------------------------
// Boundary fixup: u rows m0 of each 256-row tile (predecessor row lives in
// the previous block). 64 tiles x 1024 d / 8 per thread = 32 blocks.
// ---------------------------------------------------------------------------
__global__ __launch_bounds__(256) void conv_fix(
    const __hip_bfloat16* __restrict__ xef, const __hip_bfloat16* __restrict__ xel,
    const float* __restrict__ cw, const float* __restrict__ cb,
    __hip_bfloat16* __restrict__ u)
{
  const int i8 = (blockIdx.x * 256 + threadIdx.x) * 8;
  const int T  = i8 >> 10;        // tile 0..63
  const int d0 = i8 & 1023;
  const short8 cur = *(const short8*)((const short*)xef + T * 1024 + d0);
  short8 prv;
  if (T & 15) prv = *(const short8*)((const short*)xel + (T - 1) * 1024 + d0);
  else        prv = (short8){0, 0, 0, 0, 0, 0, 0, 0};   // l == 0
  const float4* cw4 = (const float4*)(cw + 2 * d0);
  const float4 wA = cw4[0], wB = cw4[1], wC = cw4[2], wD = cw4[3];
  const float w0a[8] = {wA.x, wA.z, wB.x, wB.z, wC.x, wC.z, wD.x, wD.z};
  const float w1a[8] = {wA.y, wA.w, wB.y, wB.w, wC.y, wC.w, wD.y, wD.w};
  const float4* cb4 = (const float4*)(cb + d0);
  const float4 b0 = cb4[0], b1 = cb4[1];
  const float ba[8] = {b0.x, b0.y, b0.z, b0.w, b1.x, b1.y, b1.z, b1.w};
  short8 outv;
#pragma unroll
  for (int k = 0; k < 8; k++) {
    const float pc = __uint_as_float(((uint32_t)(uint16_t)prv[k]) << 16);
    const float cc = __uint_as_float(((uint32_t)(uint16_t)cur[k]) << 16);
    const float v = pc * w0a[k] + cc * w1a[k] + ba[k];
    outv[k] = f2bfs(v / (1.f + __expf(-v)));
  }
  *(short8*)((short*)u + (size_t)T * 256 * 1024 + d0) = outv;
}

// ---------------------------------------------------------------------------
// x_proj GEMM, split-K x4: partial[kc][M,66] = u[M, kc-chunk] * xpw[66, kc-chunk]^T
// ---------------------------------------------------------------------------
__global__ __launch_bounds__(256) void gemm_xproj(
    const __hip_bfloat16* __restrict__ A,
    const __hip_bfloat16* __restrict__ W,
    float* __restrict__ part)
{
  constexpr int K = 1024, BK = 32, KC = K / XPJ_KS; // 256
  __shared__ short sA[128 * BK];
  __shared__ short sB[80 * BK];
  const int tid = threadIdx.x;
  const int wid = tid >> 6, lane = tid & 63;
  const int kc = blockIdx.x;
  const int m0 = blockIdx.y * 128;

  floatx4 acc[2][5];
#pragma unroll
  for (int i = 0; i < 2; i++)
#pragma unroll
    for (int j = 0; j < 5; j++) acc[i][j] = (floatx4){0.f, 0.f, 0.f, 0.f};

  const short* Ag = (const short*)A + (size_t)(m0 + (tid >> 2)) * K + kc * KC + (tid & 3) * 8;
  const int brow2 = 64 + (tid >> 2);
  const int brow2c = brow2 > 65 ? 65 : brow2;
  const short* Bg  = (const short*)W + (size_t)(tid >> 2) * K + kc * KC + (tid & 3) * 8;
  const short* Bg2 = (const short*)W + (size_t)brow2c * K + kc * KC + (tid & 3) * 8;
  const size_t rstep = (size_t)64 * K;
  const int fr = lane & 15, fq = lane >> 4;

  for (int kb = 0; kb < KC; kb += BK) {
    load16(Ag, &sA[tid * 8]);
    load16(Ag + rstep, &sA[2048 + tid * 8]);
    load16(Bg, &sB[tid * 8]);
    if (tid < 64) load16(Bg2, &sB[2048 + tid * 8]);
    Ag += BK; Bg += BK; Bg2 += BK;
    __syncthreads();

    short8 av[2], bv[5];
#pragma unroll
    for (int mt = 0; mt < 2; mt++) av[mt] = *(const short8*)&sA[(wid * 32 + mt * 16 + fr) * BK + fq * 8];
#pragma unroll
    for (int nt = 0; nt < 5; nt++) bv[nt] = *(const short8*)&sB[(nt * 16 + fr) * BK + fq * 8];
#pragma unroll
    for (int mt = 0; mt < 2; mt++)
#pragma unroll
      for (int nt = 0; nt < 5; nt++)
        acc[mt][nt] = __builtin_amdgcn_mfma_f32_16x16x32_bf16(av[mt], bv[nt], acc[mt][nt], 0, 0, 0);
    __syncthreads();
  }

  float* pp = part + (size_t)kc * Mrows * 66;
#pragma unroll
  for (int mt = 0; mt < 2; mt++) {
#pragma unroll
    for (int nt = 0; nt < 5; nt++) {
#pragma unroll
      for (int r = 0; r < 4; r++) {
        const int gm = m0 + wid * 32 + mt * 16 + fq * 4 + r;
        const int gn = nt * 16 + fr;
        if (gn < 66) pp[(size_t)gm * 66 + gn] = acc[mt][nt][r];
      }
    }
  }
}

__global__ __launch_bounds__(256) void xproj_reduce(
    const float* __restrict__ part,
    __hip_bfloat16* __restrict__ dts,
    float* __restrict__ Bs, float* __restrict__ Cs)
{
  const int i = blockIdx.x * 256 + threadIdx.x;
  if (i >= Mrows * 66) return;
  const int gm = i / 66, gn = i - gm * 66;
  float s = part[i] + part[i + (size_t)Mrows * 66]
          + part[i + (size_t)2 * Mrows * 66] + part[i + (size_t)3 * Mrows * 66];
  if (gn < 64)       dts[(size_t)gm * 64 + gn] = __float2bfloat16(s);
  else if (gn == 64) Bs[gm] = s;
  else               Cs[gm] = s;
}

// ---------------------------------------------------------------------------
// Chunked scan, D_STATE=1:  h[l] = exp(delta*A)*h[l-1] + delta*Bs*u
// CH=32 (1024 wg for p1/p3 = 4 waves/SIMD), 2 d's/thread (4B loads).
// ---------------------------------------------------------------------------
__global__ __launch_bounds__(256) void scan_p1(
    const __hip_bfloat16* __restrict__ delta, const __hip_bfloat16* __restrict__ u,
    const float* __restrict__ Bsv, const float* __restrict__ A_logs,
    float* __restrict__ carryP, float* __restrict__ carryS)
{
  const int dp = blockIdx.x * 256 + threadIdx.x;   // d-pair 0..511
  const int d  = dp * 2;
  const int c = blockIdx.y, b = blockIdx.z;
  const float2 Al = *(const float2*)(A_logs + d);
  const float Ac0 = -__expf(Al.x), Ac1 = -__expf(Al.y);
  const size_t base = ((size_t)(b * Lz + c * CH)) * Di + d;
  const float* Bp = Bsv + (size_t)b * Lz + c * CH;
  float P0 = 1.f, h0 = 0.f, P1 = 1.f, h1 = 0.f;
#pragma unroll 8
  for (int j = 0; j < CH; j++) {
    const uint32_t dv = *(const uint32_t*)((const uint16_t*)delta + base + (size_t)j * Di);
    const uint32_t uv = *(const uint32_t*)((const uint16_t*)u + base + (size_t)j * Di);
    const float dl0 = __uint_as_float(dv << 16);
    const float dl1 = __uint_as_float(dv & 0xffff0000u);
    const float uu0 = __uint_as_float(uv << 16);
    const float uu1 = __uint_as_float(uv & 0xffff0000u);
    const float bj  = Bp[j];
    const float a0 = __expf(dl0 * Ac0), a1 = __expf(dl1 * Ac1);
    h0 = a0 * h0 + dl0 * bj * uu0;
    h1 = a1 * h1 + dl1 * bj * uu1;
    P0 *= a0; P1 *= a1;
  }
  const size_t ci = ((size_t)(b * NCH + c)) * Di + d;
  *(float2*)(carryP + ci) = make_float2(P0, P1);
  *(float2*)(carryS + ci) = make_float2(h0, h1);
}

__global__ __launch_bounds__(64) void scan_p2(
    const float* __restrict__ carryP, const float* __restrict__ carryS,
    float* __restrict__ hin)
{
  const int t = blockIdx.x * 64 + threadIdx.x;   // 0..4095
  const int b = t >> 10, d = t & (Di - 1);
  float h = 0.f;
  for (int c = 0; c < NCH; c++) {
    const size_t ci = ((size_t)(b * NCH + c)) * Di + d;
    hin[ci] = h;
    h = carryP[ci] * h + carryS[ci];
  }
}

__global__ __launch_bounds__(256) void scan_p3(
    const __hip_bfloat16* __restrict__ delta, __hip_bfloat16* __restrict__ uy,
    const float* __restrict__ Bsv, const float* __restrict__ Csv,
    const float* __restrict__ A_logs, const float* __restrict__ Ds,
    const float* __restrict__ hin)
{
  const int dp = blockIdx.x * 256 + threadIdx.x;
  const int d  = dp * 2;
  const int c = blockIdx.y, b = blockIdx.z;
  const float2 Al = *(const float2*)(A_logs + d);
  const float Ac0 = -__expf(Al.x), Ac1 = -__expf(Al.y);
  const float2 Dd = *(const float2*)(Ds + d);
  const size_t base = ((size_t)(b * Lz + c * CH)) * Di + d;
  const float* Bp = Bsv + (size_t)b * Lz + c * CH;
  const float* Cp = Csv + (size_t)b * Lz + c * CH;
  const size_t ci = ((size_t)(b * NCH + c)) * Di + d;
  const float2 hh = *(const float2*)(hin + ci);
  float h0 = hh.x, h1 = hh.y;
#pragma unroll 8
  for (int j = 0; j < CH; j++) {
    const size_t ix = base + (size_t)j * Di;
    const uint32_t dv = *(const uint32_t*)((const uint16_t*)delta + ix);
    const uint32_t uv = *(const uint32_t*)((const uint16_t*)uy + ix);
    const float dl0 = __uint_as_float(dv << 16);
    const float dl1 = __uint_as_float(dv & 0xffff0000u);
    const float uu0 = __uint_as_float(uv << 16);
    const float uu1 = __uint_as_float(uv & 0xffff0000u);
    const float bj = Bp[j], cj = Cp[j];
    const float a0 = __expf(dl0 * Ac0), a1 = __expf(dl1 * Ac1);
    h0 = a0 * h0 + dl0 * bj * uu0;
    h1 = a1 * h1 + dl1 * bj * uu1;
    const float y0 = h0 * cj + uu0 * Dd.x;
    const float y1 = h1 * cj + uu1 * Dd.y;
    const uint32_t o = (uint32_t)(uint16_t)f2bfs(y0) | ((uint32_t)(uint16_t)f2bfs(y1) << 16);
    *(uint32_t*)((uint16_t*)uy + ix) = o;
  }
}

// ---------------------------------------------------------------------------
// LayerNorm over D=1024 + SiLU(z) gate -> bf16.
// ---------------------------------------------------------------------------
__global__ __launch_bounds__(256) void ln_gate(
    const __hip_bfloat16* __restrict__ y, const __hip_bfloat16* __restrict__ z,
    const float* __restrict__ lnw, const float* __restrict__ lnb,
    __hip_bfloat16* __restrict__ yg)
{
  const int row = blockIdx.x;
  const int tid = threadIdx.x;
  const int wid = tid >> 6, lane = tid & 63;
  const short4v yv = *(const short4v*)((const short*)y + (size_t)row * Di + tid * 4);
  const short4v zv4 = *(const short4v*)((const short*)z + (size_t)row * Di + tid * 4);
  float v[4];
#pragma unroll
  for (int i = 0; i < 4; i++)
    v[i] = __uint_as_float(((uint32_t)(uint16_t)yv[i]) << 16);
  float s1 = v[0] + v[1] + v[2] + v[3];
  float s2 = v[0] * v[0] + v[1] * v[1] + v[2] * v[2] + v[3] * v[3];
#pragma unroll
  for (int o = 32; o > 0; o >>= 1) {
    s1 += __shfl_down(s1, o, 64);
    s2 += __shfl_down(s2, o, 64);
  }
  __shared__ float r1[4], r2[4];
  if (lane == 0) { r1[wid] = s1; r2[wid] = s2; }
  __syncthreads();
  const float t1 = r1[0] + r1[1] + r1[2] + r1[3];
  const float t2 = r2[0] + r2[1] + r2[2] + r2[3];
  const float mu = t1 * (1.f / Di);
  const float var = t2 * (1.f / Di) - mu * mu;
  const float rstd = rsqrtf(var + 1e-5f);

  const float4 wv = ((const float4*)lnw)[tid];
  const float4 bv = ((const float4*)lnb)[tid];
  const float wa[4] = {wv.x, wv.y, wv.z, wv.w};
  const float ba[4] = {bv.x, bv.y, bv.z, bv.w};
  short4v og;
#pragma unroll
  for (int i = 0; i < 4; i++) {
    const float zz = __uint_as_float(((uint32_t)(uint16_t)zv4[i]) << 16);
    const float g = zz / (1.f + __expf(-zz));
    og[i] = f2bfs(((v[i] - mu) * rstd * wa[i] + ba[i]) * g);
  }
  *(short4v*)((short*)yg + (size_t)row * Di + tid * 4) = og;
}

// ---------------------------------------------------------------------------
// Diagnostic: fill d_out (f32) with ws_size expressed in KiB (read via absmax).
// ---------------------------------------------------------------------------
__global__ __launch_bounds__(256) void fill_diag(float* __restrict__ out, int n, float val)
{
  const int i = blockIdx.x * 256 + threadIdx.x;
  if (i < n) out[i] = val;
}

// ---------------------------------------------------------------------------
extern "C" void kernel_launch(void* const* d_in, const int* in_sizes, int n_in,
                              void* d_out, int out_size, void* d_ws, size_t ws_size,
                              hipStream_t stream)
{
  const float* x      = (const float*)d_in[0];
  const float* w_in   = (const float*)d_in[1];
  const float* conv_w = (const float*)d_in[2];
  const float* conv_b = (const float*)d_in[3];
  const float* xpw    = (const float*)d_in[4];
  const float* dtw    = (const float*)d_in[5];
  const float* dtb    = (const float*)d_in[6];
  const float* A_logs = (const float*)d_in[7];
  const float* Ds     = (const float*)d_in[8];
  const float* lnw    = (const float*)d_in[9];
  const float* lnb    = (const float*)d_in[10];
  const float* w_out  = (const float*)d_in[11];
  float* outF = (float*)d_out;   // 16.7M f32 = 64 MiB

  const size_t BF16BIG  = (size_t)Mrows * Di * sizeof(__hip_bfloat16); // 32 MiB
  const size_t NEED_RUN = 69603328;  // exact ws usage below (unchanged)

  if (ws_size < NEED_RUN) {
    fill_diag<<<(out_size + 255) / 256, 256, 0, stream>>>(
        outF, out_size, (float)(ws_size >> 10));
    return;
  }

  uint8_t* ws = (uint8_t*)d_ws;
  size_t off = 0;
  auto alloc = [&](size_t bytes) { void* p = ws + off; off += (bytes + 255) & ~(size_t)255; return p; };

  // ws layout (66.4 MiB total):
  __hip_bfloat16* slotA    = (__hip_bfloat16*)alloc(BF16BIG);   // u -> y (in-place)
  __hip_bfloat16* slotC    = (__hip_bfloat16*)alloc(BF16BIG);   // xbf -> delta -> yg
  __hip_bfloat16* w_out_bf = (__hip_bfloat16*)alloc((size_t)Dm * Di * 2);
  __hip_bfloat16* xpw_bf   = (__hip_bfloat16*)alloc((size_t)66 * Di * 2);
  __hip_bfloat16* dtw_bf   = (__hip_bfloat16*)alloc((size_t)Di * 64 * 2);
  float* Bsv = (float*)alloc((size_t)Mrows * sizeof(float));
  float* Csv = (float*)alloc((size_t)Mrows * sizeof(float));

  // d_out (64 MiB f32) scratch map (regions dead before stage 9):
  //  [0,32M):       z (alive until stage 8)
  //  [32,36M):      w_in_bf (dead after stage 1)
  //  [36,38M):      dts (bf16, dead after stage 4)
  //  [38,40M):      carryP (stage 5+)
  //  [40,42M):      carryS (overlaps dead xpj_part head)
  //  [42,44M):      hin (stage 6+, xpj dead)
  //  [44,44.25M):   xcedge first/last (stage 1 -> conv_fix; dead before xproj)
  //  [40M,57.3M):   xpj_part (stage 3 only)
  __hip_bfloat16* zbuf    = (__hip_bfloat16*)d_out;
  __hip_bfloat16* w_in_bf = (__hip_bfloat16*)((uint8_t*)d_out + 33554432);
  __hip_bfloat16* dts     = (__hip_bfloat16*)((uint8_t*)d_out + 37748736);
  float* carryP = (float*)((uint8_t*)d_out + 39845888);
  float* carryS = (float*)((uint8_t*)d_out + 41943040);
  float* hin    = (float*)((uint8_t*)d_out + 44040192);
  __hip_bfloat16* xef = (__hip_bfloat16*)((uint8_t*)d_out + 46137344);           // 128KB
  __hip_bfloat16* xel = (__hip_bfloat16*)((uint8_t*)d_out + 46137344 + 131072);  // 128KB
  float* xpj_part = (float*)((uint8_t*)d_out + 41943040);  // overlaps carryS/hin/xcedge (all dead/later)

  __hip_bfloat16* xbf   = slotC;   // stage-1 A input (dead after stage 1)
  __hip_bfloat16* ubuf  = slotA;   // u from fused gemm epilogue (+fixup); y in-place later
  __hip_bfloat16* delta = slotC;   // stage-4 out (over xbf, dead)
  __hip_bfloat16* yg    = slotC;   // stage-8 out (over delta, dead after scan_p3)

  // 0. convert f32 inputs -> bf16 working copies (one fused launch)
  cvt_all<<<(5014016 + 255) / 256, 256, 0, stream>>>(
      x, w_in, w_out, xpw, dtw, xbf, w_in_bf, w_out_bf, xpw_bf, dtw_bf);

  // 1. xz = x @ w_in^T; xc-half fused with conv+SiLU -> u (slotA); z -> d_out.
  gemm256<0><<<dim3(2 * Di / 256, Mrows / 256), 512, 0, stream>>>(
      xbf, w_in_bf, Dm, 2 * Di, ubuf, zbuf, nullptr, conv_w, conv_b, xef, xel);
  // 2. boundary rows of u (tile-first rows)
  conv_fix<<<32, 256, 0, stream>>>(xef, xel, conv_w, conv_b, ubuf);
  // 3. x_proj split-K -> partials -> reduce to dts, Bs, Cs
  gemm_xproj<<<dim3(XPJ_KS, Mrows / 128), 256, 0, stream>>>(ubuf, xpw_bf, xpj_part);
  xproj_reduce<<<(Mrows * 66 + 255) / 256, 256, 0, stream>>>(xpj_part, dts, Bsv, Csv);
  // 4. delta = softplus(dts @ dtw^T + bias) -> slotC (xbf dead)
  gemm128<1><<<dim3(Di / 128, Mrows / 128), 256, 0, stream>>>(
      dts, dtw_bf, 64, Di, delta, nullptr, nullptr, dtb);
  // 5-7. chunked scan (CH=32); y written in-place over u
  scan_p1<<<dim3(Di / 512, NCH, Bz), 256, 0, stream>>>(delta, ubuf, Bsv, A_logs, carryP, carryS);
  scan_p2<<<(Bz * Di) / 64, 64, 0, stream>>>(carryP, carryS, hin);
  scan_p3<<<dim3(Di / 512, NCH, Bz), 256, 0, stream>>>(delta, ubuf, Bsv, Csv, A_logs, Ds, hin);
  // 8. layernorm + silu(z) gate -> yg (slotC; delta dead)
  ln_gate<<<Mrows, 256, 0, stream>>>(ubuf, zbuf, lnw, lnb, yg);
  // 9. out = yg @ w_out^T -> d_out f32 (overwrites all d_out scratch — dead)
  gemm256<1><<<dim3(Dm / 256, Mrows / 256), 512, 0, stream>>>(
      yg, w_out_bf, Di, Dm, nullptr, nullptr, outF, nullptr, nullptr, nullptr, nullptr);
}